// Round 1
// baseline (496.673 us; speedup 1.0000x reference)
//
#include <hip/hip_runtime.h>
#include <math.h>

#define N_PTS 8192
#define HIDDEN 256
#define PPB 4                  // points per block (1 wave per point)
#define NBLK (N_PTS / PPB)
#define NBINS 64

typedef float f4 __attribute__((ext_vector_type(4)));

// ---------------------------------------------------------------------------
// Main kernel: second-order forward-mode propagation through the MLP + physics
// Streams: 0=value, 1=d/dx0, 2=d/dx1, 3=d/dt, 4=d2/dx0^2, 5=d2/dx0dx1, 6=d2/dx1^2
// ---------------------------------------------------------------------------
__global__ __launch_bounds__(256, 2)
void pinn_main(const float* __restrict__ W0, const float* __restrict__ b0,
               const float* __restrict__ W1, const float* __restrict__ b1,
               const float* __restrict__ W2, const float* __restrict__ b2,
               const float* __restrict__ W3, const float* __restrict__ b3,
               const float* __restrict__ W4, const float* __restrict__ b4,
               const float* __restrict__ xin, const float* __restrict__ tin,
               float* __restrict__ bins)
{
    __shared__ float Hs[PPB][7][HIDDEN];   // 28 KB: activation streams
    __shared__ float Wt[32][HIDDEN];       // 32 KB: W chunk (32 rows)

    const int tid  = threadIdx.x;
    const int lane = tid & 63;
    const int p    = tid >> 6;             // wave index == point-in-block
    const int c0   = lane * 4;             // 4 output columns per lane
    const int pt   = blockIdx.x * PPB + p;

    const float x0 = xin[pt * 2 + 0];
    const float x1 = xin[pt * 2 + 1];
    const float tt = tin[pt];

    // ---- layer 0 (3 -> 256): tangents of input are unit vectors ----
    #pragma unroll
    for (int jj = 0; jj < 4; ++jj) {
        const int j = c0 + jj;
        const float w0 = W0[j], w1 = W0[HIDDEN + j], w2 = W0[2 * HIDDEN + j];
        const float z  = fmaf(x0, w0, fmaf(x1, w1, fmaf(tt, w2, b0[j])));
        const float a  = tanhf(z);
        const float st = 1.f - a * a;
        const float m2 = -2.f * a * st;
        Hs[p][0][j] = a;
        Hs[p][1][j] = st * w0;
        Hs[p][2][j] = st * w1;
        Hs[p][3][j] = st * w2;
        Hs[p][4][j] = m2 * w0 * w0;
        Hs[p][5][j] = m2 * w0 * w1;
        Hs[p][6][j] = m2 * w1 * w1;
    }

    const float* const Wl[3] = {W1, W2, W3};
    const float* const blv[3] = {b1, b2, b3};

    // ---- hidden layers (256 -> 256) x3 ----
    for (int l = 0; l < 3; ++l) {
        const float* __restrict__ Wg = Wl[l];
        float acc[7][4];
        #pragma unroll
        for (int s = 0; s < 7; ++s)
            #pragma unroll
            for (int jj = 0; jj < 4; ++jj) acc[s][jj] = 0.f;

        for (int chunk = 0; chunk < 8; ++chunk) {
            __syncthreads();               // protect Wt reuse
            // stage 32 rows (8192 floats) of W into LDS, coalesced
            #pragma unroll
            for (int k = 0; k < 8; ++k) {
                const int f = tid * 4 + k * 1024;
                *(f4*)(&Wt[0][0] + f) = *(const f4*)(Wg + chunk * 8192 + f);
            }
            __syncthreads();
            // accumulate z += h_tile @ W_tile
            #pragma unroll
            for (int stp = 0; stp < 8; ++stp) {
                const int ib = chunk * 32 + stp * 4;
                f4 hv[7];
                #pragma unroll
                for (int s = 0; s < 7; ++s)
                    hv[s] = *(const f4*)&Hs[p][s][ib];      // wave-broadcast
                f4 wv[4];
                #pragma unroll
                for (int k = 0; k < 4; ++k)
                    wv[k] = *(const f4*)&Wt[stp * 4 + k][c0]; // conflict-free
                #pragma unroll
                for (int s = 0; s < 7; ++s)
                    #pragma unroll
                    for (int k = 0; k < 4; ++k)
                        #pragma unroll
                        for (int jj = 0; jj < 4; ++jj)
                            acc[s][jj] = fmaf(hv[s][k], wv[k][jj], acc[s][jj]);
            }
        }
        __syncthreads();                   // everyone done reading Hs
        // tanh nonlinearity on all 7 streams, write back
        #pragma unroll
        for (int jj = 0; jj < 4; ++jj) {
            const int j = c0 + jj;
            const float zv = acc[0][jj] + blv[l][j];
            const float a  = tanhf(zv);
            const float st = 1.f - a * a;
            const float m2 = -2.f * a * st;
            const float z1 = acc[1][jj], z2 = acc[2][jj], z3 = acc[3][jj];
            Hs[p][0][j] = a;
            Hs[p][1][j] = st * z1;
            Hs[p][2][j] = st * z2;
            Hs[p][3][j] = st * z3;
            Hs[p][4][j] = fmaf(m2 * z1, z1, st * acc[4][jj]);
            Hs[p][5][j] = fmaf(m2 * z1, z2, st * acc[5][jj]);
            Hs[p][6][j] = fmaf(m2 * z2, z2, st * acc[6][jj]);
        }
    }
    __syncthreads();

    // ---- final layer (256 -> 3): 21 dot products per point via wave reduce ----
    float part[7][3];
    #pragma unroll
    for (int s = 0; s < 7; ++s)
        #pragma unroll
        for (int m = 0; m < 3; ++m) part[s][m] = 0.f;

    const int i0 = lane * 4;
    f4 hvf[7];
    #pragma unroll
    for (int s = 0; s < 7; ++s) hvf[s] = *(const f4*)&Hs[p][s][i0];
    float w4v[4][3];
    #pragma unroll
    for (int k = 0; k < 4; ++k)
        #pragma unroll
        for (int m = 0; m < 3; ++m) w4v[k][m] = W4[(i0 + k) * 3 + m];
    #pragma unroll
    for (int s = 0; s < 7; ++s)
        #pragma unroll
        for (int k = 0; k < 4; ++k)
            #pragma unroll
            for (int m = 0; m < 3; ++m)
                part[s][m] = fmaf(hvf[s][k], w4v[k][m], part[s][m]);

    #pragma unroll
    for (int s = 0; s < 7; ++s)
        #pragma unroll
        for (int m = 0; m < 3; ++m) {
            float v = part[s][m];
            #pragma unroll
            for (int off = 32; off > 0; off >>= 1) v += __shfl_xor(v, off);
            part[s][m] = v;                // all lanes hold the sum
        }

    // ---- physics (all lanes redundantly; lane 0 accumulates) ----
    const float V0 = part[0][0] + b4[0];
    const float V1 = part[0][1] + b4[1];
    const float V2 = part[0][2] + b4[2];
    const float J00 = part[1][0], J01 = part[2][0], J0t = part[3][0];
    const float J10 = part[1][1], J11 = part[2][1];
    const float J20 = part[1][2], J21 = part[2][2];
    const float H000 = part[4][0], H001 = part[5][0], H011 = part[6][0];
    const float H100 = part[4][1], H101 = part[5][1], H111 = part[6][1];
    const float H200 = part[4][2], H201 = part[5][2], H211 = part[6][2];
    (void)H001;

    const float phi = 1.f / (1.f + expf(-V0));
    const float om  = 1.f - phi;
    const float sp  = phi * om;                  // sigmoid'
    const float spp = sp * (1.f - 2.f * phi);    // sigmoid''
    const float phx0 = sp * J00, phx1 = sp * J01, dphidt = sp * J0t;
    const float lap = spp * (J00 * J00 + J01 * J01) + sp * (H000 + H011);

    const float ld = tt;                          // loading(t) = t
    const float q = x1 * (x1 - 1.f), qp = 2.f * x1 - 1.f;   // q'' = 2

    // first derivatives of u wrt x
    const float ux0 = q * J10 * ld * (1.f / 3.f);
    const float ux1 = (qp * V1 + q * J11) * ld * (1.f / 3.f);
    const float uy0 = q * J20 * ld;
    const float uy1 = (qp * V2 + q * J21) * ld + ld;

    const float e00 = ux0, e11 = uy1, e01 = 0.5f * (ux1 + uy0);
    const float tr = e00 + e11;

    // second derivatives of u wrt x
    const float ux_00 = q * H100 * ld * (1.f / 3.f);
    const float ux_01 = (qp * J10 + q * H101) * ld * (1.f / 3.f);
    const float ux_11 = (2.f * V1 + 2.f * qp * J11 + q * H111) * ld * (1.f / 3.f);
    const float uy_00 = q * H200 * ld;
    const float uy_01 = (qp * J20 + q * H201) * ld;
    const float uy_11 = (2.f * V2 + 2.f * qp * J21 + q * H211) * ld;

    const float de00_0 = ux_00, de00_1 = ux_01;
    const float de11_0 = uy_01, de11_1 = uy_11;
    const float de01_0 = 0.5f * (ux_01 + uy_00), de01_1 = 0.5f * (ux_11 + uy_01);
    const float dtr_0 = de00_0 + de11_0, dtr_1 = de00_1 + de11_1;

    const float kk = 2.f;                         // LAMBDA + 2*MU/DIM
    const float rtr = fmaxf(tr, 0.f), rntr = fmaxf(-tr, 0.f);
    const float Hp = (tr > 0.f) ? 1.f : 0.f, Hn = (tr < 0.f) ? 1.f : 0.f;

    const float dv = 0.5f * (e00 - e11);
    const float sp00 = kk * rtr + 2.f * dv;
    const float sp11 = kk * rtr - 2.f * dv;
    const float sp01 = 2.f * e01;
    const float snd  = -kk * rntr;                // sigma_neg diagonal

    const float dsp00_0 = kk * Hp * dtr_0 + 2.f * (de00_0 - 0.5f * dtr_0);
    const float dsp00_1 = kk * Hp * dtr_1 + 2.f * (de00_1 - 0.5f * dtr_1);
    const float dsp11_0 = kk * Hp * dtr_0 + 2.f * (de11_0 - 0.5f * dtr_0);
    const float dsp11_1 = kk * Hp * dtr_1 + 2.f * (de11_1 - 0.5f * dtr_1);
    const float dsp01_0 = 2.f * de01_0, dsp01_1 = 2.f * de01_1;
    const float dsn_0 = kk * Hn * dtr_0, dsn_1 = kk * Hn * dtr_1;

    const float c  = om * om, g = c + 1e-6f;
    const float dc0 = -2.f * om * phx0, dc1 = -2.f * om * phx1;
    const float gpc = g + c, cg = c * g;

    // res_i = sum_j d_j [ c*g*sigma_p_ij + c*sigma_n_ij ]
    const float res0 = dc0 * gpc * sp00 + cg * dsp00_0 + dc0 * snd + c * dsn_0
                     + dc1 * gpc * sp01 + cg * dsp01_1;
    const float res1 = dc0 * gpc * sp01 + cg * dsp01_0
                     + dc1 * gpc * sp11 + cg * dsp11_1 + dc1 * snd + c * dsn_1;

    const float psip = rtr * rtr + 0.5f * (e00 - e11) * (e00 - e11) + 2.f * e01 * e01;
    const float psin = rntr * rntr;

    const float GCc = 0.0027f, LL = 0.02f;
    const float pf = GCc * (phi / LL - LL * lap) - 2.f * om * psip;
    const bool maskp = (fabsf(dphidt) <= 1e-3f) && (fabsf(phi - 1.f) > 1e-3f);
    const bool maskn = fabsf(phi - 1.f) <= 1e-3f;
    const float respf = maskp ? fmaxf(-pf, 0.f) : (maskn ? fmaxf(pf, 0.f) : pf);

    const float rese = om * 2.f * psip + psin
                     + GCc * (phi * phi / (2.f * LL)
                              + 0.5f * LL * (phx0 * phx0 + phx1 * phx1));
    const float irr = fmaxf(-dphidt, 0.f);

    if (lane == 0) {
        float* bin = bins + (blockIdx.x & (NBINS - 1)) * 8;
        atomicAdd(bin + 0, res0 * res0);
        atomicAdd(bin + 1, res1 * res1);
        atomicAdd(bin + 2, respf * respf);
        atomicAdd(bin + 3, rese);
        atomicAdd(bin + 4, irr);
    }
}

// ---------------------------------------------------------------------------
// Finalize: combine bins into the 4 losses
// ---------------------------------------------------------------------------
__global__ void pinn_finalize(const float* __restrict__ bins, float* __restrict__ out)
{
    if (threadIdx.x == 0 && blockIdx.x == 0) {
        float S[5] = {0.f, 0.f, 0.f, 0.f, 0.f};
        for (int b = 0; b < NBINS; ++b)
            for (int k = 0; k < 5; ++k) S[k] += bins[b * 8 + k];
        const float inv_n = 1.f / (float)N_PTS;
        const float mse0 = S[0] * inv_n, mse1 = S[1] * inv_n;
        const float wm = 0.5f * (mse0 + mse1);
        out[0] = wm * mse0 / (mse0 + 1e-6f) + wm * mse1 / (mse1 + 1e-6f);
        out[1] = S[2] * inv_n;
        out[2] = logf(S[3]);
        out[3] = S[4] * inv_n;
    }
}

// ---------------------------------------------------------------------------
extern "C" void kernel_launch(void* const* d_in, const int* in_sizes, int n_in,
                              void* d_out, int out_size, void* d_ws, size_t ws_size,
                              hipStream_t stream)
{
    const float *W[5], *b[5];
    if (in_sizes[1] == HIDDEN) {
        // dict order: W0,b0,W1,b1,...
        for (int i = 0; i < 5; ++i) {
            W[i] = (const float*)d_in[2 * i];
            b[i] = (const float*)d_in[2 * i + 1];
        }
    } else {
        // signature order: W0..W4, b0..b4
        for (int i = 0; i < 5; ++i) {
            W[i] = (const float*)d_in[i];
            b[i] = (const float*)d_in[5 + i];
        }
    }
    const float* x = (const float*)d_in[10];
    const float* t = (const float*)d_in[11];
    float* bins = (float*)d_ws;

    hipMemsetAsync(bins, 0, NBINS * 8 * sizeof(float), stream);
    pinn_main<<<NBLK, 256, 0, stream>>>(W[0], b[0], W[1], b[1], W[2], b[2],
                                        W[3], b[3], W[4], b[4], x, t, bins);
    pinn_finalize<<<1, 64, 0, stream>>>(bins, (float*)d_out);
}

// Round 3
// 452.486 us; speedup vs baseline: 1.0977x; 1.0977x over previous
//
#include <hip/hip_runtime.h>
#include <math.h>

#define N_PTS 8192
#define HIDDEN 256
#define PPB 4                  // points per block (1 wave per point)
#define NBLK (N_PTS / PPB)
#define NBINS 64

typedef float f4 __attribute__((ext_vector_type(4)));

// ---------------------------------------------------------------------------
// Main kernel: second-order forward-mode propagation through the MLP + physics
// Streams: 0=value, 1=d/dx0, 2=d/dx1, 3=d/dt, 4=d2/dx0^2, 5=d2/dx0dx1, 6=d2/dx1^2
// W is read straight from global (L2-resident, 790 KB total); LDS holds only
// the per-wave H state, read via broadcast. No __syncthreads needed: each wave
// touches only its own Hs[p] slice.
// ---------------------------------------------------------------------------
__global__ __launch_bounds__(256, 4)
void pinn_main(const float* __restrict__ W0, const float* __restrict__ b0,
               const float* __restrict__ W1, const float* __restrict__ b1,
               const float* __restrict__ W2, const float* __restrict__ b2,
               const float* __restrict__ W3, const float* __restrict__ b3,
               const float* __restrict__ W4, const float* __restrict__ b4,
               const float* __restrict__ xin, const float* __restrict__ tin,
               float* __restrict__ bins)
{
    __shared__ float Hs[PPB][7][HIDDEN];   // 28 KB: activation streams

    const int tid  = threadIdx.x;
    const int lane = tid & 63;
    const int p    = tid >> 6;             // wave index == point-in-block
    const int c0   = lane * 4;             // 4 output columns per lane
    const int pt   = blockIdx.x * PPB + p;

    const float x0 = xin[pt * 2 + 0];
    const float x1 = xin[pt * 2 + 1];
    const float tt = tin[pt];

    // ---- layer 0 (3 -> 256): tangents of input are unit vectors ----
    {
        f4 v[7];
        #pragma unroll
        for (int jj = 0; jj < 4; ++jj) {
            const int j = c0 + jj;
            const float w0 = W0[j], w1 = W0[HIDDEN + j], w2 = W0[2 * HIDDEN + j];
            const float z  = fmaf(x0, w0, fmaf(x1, w1, fmaf(tt, w2, b0[j])));
            const float a  = tanhf(z);
            const float st = 1.f - a * a;
            const float m2 = -2.f * a * st;
            v[0][jj] = a;
            v[1][jj] = st * w0;
            v[2][jj] = st * w1;
            v[3][jj] = st * w2;
            v[4][jj] = m2 * w0 * w0;
            v[5][jj] = m2 * w0 * w1;
            v[6][jj] = m2 * w1 * w1;
        }
        #pragma unroll
        for (int s = 0; s < 7; ++s)
            *(f4*)&Hs[p][s][c0] = v[s];    // ds_write_b128, conflict-free
    }

    const float* const Wl[3] = {W1, W2, W3};
    const float* const blv[3] = {b1, b2, b3};

    // ---- hidden layers (256 -> 256) x3 ----
    for (int l = 0; l < 3; ++l) {
        const float* __restrict__ Wg = Wl[l];
        float acc[7][4];
        #pragma unroll
        for (int s = 0; s < 7; ++s)
            #pragma unroll
            for (int jj = 0; jj < 4; ++jj) acc[s][jj] = 0.f;

        #pragma unroll 4
        for (int kb = 0; kb < 64; ++kb) {
            const int ib = kb * 4;
            f4 hv[7];
            #pragma unroll
            for (int s = 0; s < 7; ++s)
                hv[s] = *(const f4*)&Hs[p][s][ib];          // wave-broadcast read
            f4 wv[4];
            #pragma unroll
            for (int k = 0; k < 4; ++k)
                wv[k] = *(const f4*)(Wg + (ib + k) * HIDDEN + c0); // coalesced, L1/L2
            #pragma unroll
            for (int s = 0; s < 7; ++s)
                #pragma unroll
                for (int k = 0; k < 4; ++k)
                    #pragma unroll
                    for (int jj = 0; jj < 4; ++jj)
                        acc[s][jj] = fmaf(hv[s][k], wv[k][jj], acc[s][jj]);
        }

        // tanh nonlinearity on all 7 streams, write back (b128, conflict-free)
        f4 nv[7];
        #pragma unroll
        for (int jj = 0; jj < 4; ++jj) {
            const int j = c0 + jj;
            const float zv = acc[0][jj] + blv[l][j];
            const float a  = tanhf(zv);
            const float st = 1.f - a * a;
            const float m2 = -2.f * a * st;
            const float z1 = acc[1][jj], z2 = acc[2][jj], z3 = acc[3][jj];
            nv[0][jj] = a;
            nv[1][jj] = st * z1;
            nv[2][jj] = st * z2;
            nv[3][jj] = st * z3;
            nv[4][jj] = fmaf(m2 * z1, z1, st * acc[4][jj]);
            nv[5][jj] = fmaf(m2 * z1, z2, st * acc[5][jj]);
            nv[6][jj] = fmaf(m2 * z2, z2, st * acc[6][jj]);
        }
        #pragma unroll
        for (int s = 0; s < 7; ++s)
            *(f4*)&Hs[p][s][c0] = nv[s];
    }

    // ---- final layer (256 -> 3): 21 dot products per point via wave reduce ----
    float part[7][3];
    #pragma unroll
    for (int s = 0; s < 7; ++s)
        #pragma unroll
        for (int m = 0; m < 3; ++m) part[s][m] = 0.f;

    const int i0 = lane * 4;
    f4 hvf[7];
    #pragma unroll
    for (int s = 0; s < 7; ++s) hvf[s] = *(const f4*)&Hs[p][s][i0];
    float w4v[4][3];
    #pragma unroll
    for (int k = 0; k < 4; ++k)
        #pragma unroll
        for (int m = 0; m < 3; ++m) w4v[k][m] = W4[(i0 + k) * 3 + m];
    #pragma unroll
    for (int s = 0; s < 7; ++s)
        #pragma unroll
        for (int k = 0; k < 4; ++k)
            #pragma unroll
            for (int m = 0; m < 3; ++m)
                part[s][m] = fmaf(hvf[s][k], w4v[k][m], part[s][m]);

    #pragma unroll
    for (int s = 0; s < 7; ++s)
        #pragma unroll
        for (int m = 0; m < 3; ++m) {
            float v = part[s][m];
            #pragma unroll
            for (int off = 32; off > 0; off >>= 1) v += __shfl_xor(v, off);
            part[s][m] = v;                // all lanes hold the sum
        }

    // ---- physics (all lanes redundantly; lane 0 accumulates) ----
    const float V0 = part[0][0] + b4[0];
    const float V1 = part[0][1] + b4[1];
    const float V2 = part[0][2] + b4[2];
    const float J00 = part[1][0], J01 = part[2][0], J0t = part[3][0];
    const float J10 = part[1][1], J11 = part[2][1];
    const float J20 = part[1][2], J21 = part[2][2];
    const float H000 = part[4][0], H011 = part[6][0];
    const float H100 = part[4][1], H101 = part[5][1], H111 = part[6][1];
    const float H200 = part[4][2], H201 = part[5][2], H211 = part[6][2];

    const float phi = 1.f / (1.f + expf(-V0));
    const float om  = 1.f - phi;
    const float sp  = phi * om;                  // sigmoid'
    const float spp = sp * (1.f - 2.f * phi);    // sigmoid''
    const float phx0 = sp * J00, phx1 = sp * J01, dphidt = sp * J0t;
    const float lap = spp * (J00 * J00 + J01 * J01) + sp * (H000 + H011);

    const float ld = tt;                          // loading(t) = t
    const float q = x1 * (x1 - 1.f), qp = 2.f * x1 - 1.f;   // q'' = 2

    // first derivatives of u wrt x
    const float ux0 = q * J10 * ld * (1.f / 3.f);
    const float ux1 = (qp * V1 + q * J11) * ld * (1.f / 3.f);
    const float uy0 = q * J20 * ld;
    const float uy1 = (qp * V2 + q * J21) * ld + ld;

    const float e00 = ux0, e11 = uy1, e01 = 0.5f * (ux1 + uy0);
    const float tr = e00 + e11;

    // second derivatives of u wrt x
    const float ux_00 = q * H100 * ld * (1.f / 3.f);
    const float ux_01 = (qp * J10 + q * H101) * ld * (1.f / 3.f);
    const float ux_11 = (2.f * V1 + 2.f * qp * J11 + q * H111) * ld * (1.f / 3.f);
    const float uy_00 = q * H200 * ld;
    const float uy_01 = (qp * J20 + q * H201) * ld;
    const float uy_11 = (2.f * V2 + 2.f * qp * J21 + q * H211) * ld;

    const float de00_0 = ux_00, de00_1 = ux_01;
    const float de11_0 = uy_01, de11_1 = uy_11;
    const float de01_0 = 0.5f * (ux_01 + uy_00), de01_1 = 0.5f * (ux_11 + uy_01);
    const float dtr_0 = de00_0 + de11_0, dtr_1 = de00_1 + de11_1;

    const float kk = 2.f;                         // LAMBDA + 2*MU/DIM
    const float rtr = fmaxf(tr, 0.f), rntr = fmaxf(-tr, 0.f);
    const float Hp = (tr > 0.f) ? 1.f : 0.f, Hn = (tr < 0.f) ? 1.f : 0.f;

    const float dv = 0.5f * (e00 - e11);
    const float sp00 = kk * rtr + 2.f * dv;
    const float sp11 = kk * rtr - 2.f * dv;
    const float sp01 = 2.f * e01;
    const float snd  = -kk * rntr;                // sigma_neg diagonal

    const float dsp00_0 = kk * Hp * dtr_0 + 2.f * (de00_0 - 0.5f * dtr_0);
    const float dsp01_0 = 2.f * de01_0;
    const float dsp01_1 = 2.f * de01_1;
    const float dsp11_1 = kk * Hp * dtr_1 + 2.f * (de11_1 - 0.5f * dtr_1);
    const float dsn_0 = kk * Hn * dtr_0, dsn_1 = kk * Hn * dtr_1;

    const float c  = om * om, g = c + 1e-6f;
    const float dc0 = -2.f * om * phx0, dc1 = -2.f * om * phx1;
    const float gpc = g + c, cg = c * g;

    // res_i = sum_j d_j [ c*g*sigma_p_ij + c*sigma_n_ij ]
    const float res0 = dc0 * gpc * sp00 + cg * dsp00_0 + dc0 * snd + c * dsn_0
                     + dc1 * gpc * sp01 + cg * dsp01_1;
    const float res1 = dc0 * gpc * sp01 + cg * dsp01_0
                     + dc1 * gpc * sp11 + cg * dsp11_1 + dc1 * snd + c * dsn_1;

    const float psip = rtr * rtr + 0.5f * (e00 - e11) * (e00 - e11) + 2.f * e01 * e01;
    const float psin = rntr * rntr;

    const float GCc = 0.0027f, LL = 0.02f;
    const float pf = GCc * (phi / LL - LL * lap) - 2.f * om * psip;
    const bool maskp = (fabsf(dphidt) <= 1e-3f) && (fabsf(phi - 1.f) > 1e-3f);
    const bool maskn = fabsf(phi - 1.f) <= 1e-3f;
    const float respf = maskp ? fmaxf(-pf, 0.f) : (maskn ? fmaxf(pf, 0.f) : pf);

    const float rese = om * 2.f * psip + psin
                     + GCc * (phi * phi / (2.f * LL)
                              + 0.5f * LL * (phx0 * phx0 + phx1 * phx1));
    const float irr = fmaxf(-dphidt, 0.f);

    if (lane == 0) {
        float* bin = bins + (blockIdx.x & (NBINS - 1)) * 8;
        atomicAdd(bin + 0, res0 * res0);
        atomicAdd(bin + 1, res1 * res1);
        atomicAdd(bin + 2, respf * respf);
        atomicAdd(bin + 3, rese);
        atomicAdd(bin + 4, irr);
    }
}

// ---------------------------------------------------------------------------
// Finalize: combine bins into the 4 losses
// ---------------------------------------------------------------------------
__global__ void pinn_finalize(const float* __restrict__ bins, float* __restrict__ out)
{
    if (threadIdx.x == 0 && blockIdx.x == 0) {
        float S[5] = {0.f, 0.f, 0.f, 0.f, 0.f};
        for (int b = 0; b < NBINS; ++b)
            for (int k = 0; k < 5; ++k) S[k] += bins[b * 8 + k];
        const float inv_n = 1.f / (float)N_PTS;
        const float mse0 = S[0] * inv_n, mse1 = S[1] * inv_n;
        const float wm = 0.5f * (mse0 + mse1);
        out[0] = wm * mse0 / (mse0 + 1e-6f) + wm * mse1 / (mse1 + 1e-6f);
        out[1] = S[2] * inv_n;
        out[2] = logf(S[3]);
        out[3] = S[4] * inv_n;
    }
}

// ---------------------------------------------------------------------------
extern "C" void kernel_launch(void* const* d_in, const int* in_sizes, int n_in,
                              void* d_out, int out_size, void* d_ws, size_t ws_size,
                              hipStream_t stream)
{
    const float *W[5], *b[5];
    if (in_sizes[1] == HIDDEN) {
        // dict order: W0,b0,W1,b1,...
        for (int i = 0; i < 5; ++i) {
            W[i] = (const float*)d_in[2 * i];
            b[i] = (const float*)d_in[2 * i + 1];
        }
    } else {
        // signature order: W0..W4, b0..b4
        for (int i = 0; i < 5; ++i) {
            W[i] = (const float*)d_in[i];
            b[i] = (const float*)d_in[5 + i];
        }
    }
    const float* x = (const float*)d_in[10];
    const float* t = (const float*)d_in[11];
    float* bins = (float*)d_ws;

    hipMemsetAsync(bins, 0, NBINS * 8 * sizeof(float), stream);
    pinn_main<<<NBLK, 256, 0, stream>>>(W[0], b[0], W[1], b[1], W[2], b[2],
                                        W[3], b[3], W[4], b[4], x, t, bins);
    pinn_finalize<<<1, 64, 0, stream>>>(bins, (float*)d_out);
}

// Round 4
// 401.614 us; speedup vs baseline: 1.2367x; 1.1267x over previous
//
#include <hip/hip_runtime.h>
#include <math.h>

#define N_PTS 8192
#define HIDDEN 256
#define PPB 4                  // points per block (2 waves x 2 points/wave)
#define THREADS 128
#define NBLK (N_PTS / PPB)     // 2048
#define NBINS 64

typedef float f4 __attribute__((ext_vector_type(4)));

// ---------------------------------------------------------------------------
// Second-order forward-mode propagation + physics.
// Streams: 0=value, 1=d/dx0, 2=d/dx1, 3=d/dt, 4=d2/dx0^2, 5=d2/dx0dx1, 6=d2/dx1^2
// Wave = 2 points (lanes 0-31 -> point A, 32-63 -> point B); each lane owns
// 8 output columns: [la*4 .. la*4+4) and [128+la*4 .. 128+la*4+4), la=lane&31.
// This doubles FMAs per broadcast ds_read (LDS-pipe was the r3 bottleneck:
// 7 b128 broadcasts per 4-k step vs 224 VALU-cyc -> 1.5x oversubscribed;
// now 448 VALU-cyc per 7 reads -> 0.75x).
// W read from global (L2-resident). No barriers: waves touch only own Hs[p].
// ---------------------------------------------------------------------------
__global__ __launch_bounds__(THREADS, 2)
void pinn_main(const float* __restrict__ W0, const float* __restrict__ b0,
               const float* __restrict__ W1, const float* __restrict__ b1,
               const float* __restrict__ W2, const float* __restrict__ b2,
               const float* __restrict__ W3, const float* __restrict__ b3,
               const float* __restrict__ W4, const float* __restrict__ b4,
               const float* __restrict__ xin, const float* __restrict__ tin,
               float* __restrict__ bins)
{
    __shared__ float Hs[PPB][7][HIDDEN];   // 28 KB

    const int tid  = threadIdx.x;
    const int lane = tid & 63;
    const int wid  = tid >> 6;             // wave in block: 0..1
    const int half = (lane >> 5) & 1;      // which point of the wave
    const int la   = lane & 31;
    const int p    = wid * 2 + half;       // point-in-block: 0..3
    const int c0a  = la * 4;               // first column group
    const int c0b  = c0a + 128;            // second column group
    const int pt   = blockIdx.x * PPB + p;

    const float x0 = xin[pt * 2 + 0];
    const float x1 = xin[pt * 2 + 1];
    const float tt = tin[pt];

    // ---- layer 0 (3 -> 256): input tangents are unit vectors ----
    {
        f4 v[7][2];
        #pragma unroll
        for (int g = 0; g < 2; ++g) {
            const int jb = g ? c0b : c0a;
            const f4 w0 = *(const f4*)(W0 + jb);
            const f4 w1 = *(const f4*)(W0 + HIDDEN + jb);
            const f4 w2 = *(const f4*)(W0 + 2 * HIDDEN + jb);
            const f4 bb = *(const f4*)(b0 + jb);
            #pragma unroll
            for (int jj = 0; jj < 4; ++jj) {
                const float z  = fmaf(x0, w0[jj], fmaf(x1, w1[jj], fmaf(tt, w2[jj], bb[jj])));
                const float a  = tanhf(z);
                const float st = 1.f - a * a;
                const float m2 = -2.f * a * st;
                v[0][g][jj] = a;
                v[1][g][jj] = st * w0[jj];
                v[2][g][jj] = st * w1[jj];
                v[3][g][jj] = st * w2[jj];
                v[4][g][jj] = m2 * w0[jj] * w0[jj];
                v[5][g][jj] = m2 * w0[jj] * w1[jj];
                v[6][g][jj] = m2 * w1[jj] * w1[jj];
            }
        }
        #pragma unroll
        for (int s = 0; s < 7; ++s) {
            *(f4*)&Hs[p][s][c0a] = v[s][0];
            *(f4*)&Hs[p][s][c0b] = v[s][1];
        }
    }

    const float* const Wl[3]  = {W1, W2, W3};
    const float* const blv[3] = {b1, b2, b3};

    // ---- hidden layers (256 -> 256) x3 ----
    for (int l = 0; l < 3; ++l) {
        const float* __restrict__ Wg = Wl[l];
        float acc[7][8];
        #pragma unroll
        for (int s = 0; s < 7; ++s)
            #pragma unroll
            for (int jj = 0; jj < 8; ++jj) acc[s][jj] = 0.f;

        #pragma unroll 2
        for (int kb = 0; kb < 64; ++kb) {
            const int ib = kb * 4;
            f4 hv[7];
            #pragma unroll
            for (int s = 0; s < 7; ++s)
                hv[s] = *(const f4*)&Hs[p][s][ib];   // broadcast (2 addrs/wave: free)
            f4 wa[4], wb[4];
            #pragma unroll
            for (int k = 0; k < 4; ++k) {
                wa[k] = *(const f4*)(Wg + (ib + k) * HIDDEN + c0a); // cols 0-127, contiguous
                wb[k] = *(const f4*)(Wg + (ib + k) * HIDDEN + c0b); // cols 128-255
            }
            #pragma unroll
            for (int s = 0; s < 7; ++s)
                #pragma unroll
                for (int k = 0; k < 4; ++k)
                    #pragma unroll
                    for (int jj = 0; jj < 4; ++jj) {
                        acc[s][jj]     = fmaf(hv[s][k], wa[k][jj], acc[s][jj]);
                        acc[s][4 + jj] = fmaf(hv[s][k], wb[k][jj], acc[s][4 + jj]);
                    }
        }

        // tanh nonlinearity on all 7 streams, write back
        #pragma unroll
        for (int g = 0; g < 2; ++g) {
            const int jb = g ? c0b : c0a;
            const f4 bb = *(const f4*)(blv[l] + jb);
            f4 nv[7];
            #pragma unroll
            for (int jj = 0; jj < 4; ++jj) {
                const int aj = g * 4 + jj;
                const float zv = acc[0][aj] + bb[jj];
                const float a  = tanhf(zv);
                const float st = 1.f - a * a;
                const float m2 = -2.f * a * st;
                const float z1 = acc[1][aj], z2 = acc[2][aj], z3 = acc[3][aj];
                nv[0][jj] = a;
                nv[1][jj] = st * z1;
                nv[2][jj] = st * z2;
                nv[3][jj] = st * z3;
                nv[4][jj] = fmaf(m2 * z1, z1, st * acc[4][aj]);
                nv[5][jj] = fmaf(m2 * z1, z2, st * acc[5][aj]);
                nv[6][jj] = fmaf(m2 * z2, z2, st * acc[6][aj]);
            }
            #pragma unroll
            for (int s = 0; s < 7; ++s)
                *(f4*)&Hs[p][s][jb] = nv[s];
        }
    }

    // ---- final layer (256 -> 3): partial dots over the lane's 8 rows ----
    float part[7][3];
    #pragma unroll
    for (int s = 0; s < 7; ++s)
        #pragma unroll
        for (int m = 0; m < 3; ++m) part[s][m] = 0.f;

    {
        f4 h0[7], h1[7];
        #pragma unroll
        for (int s = 0; s < 7; ++s) {
            h0[s] = *(const f4*)&Hs[p][s][c0a];
            h1[s] = *(const f4*)&Hs[p][s][c0b];
        }
        // W4 rows c0a..c0a+3 (12 floats) and c0b..c0b+3 (12 floats)
        f4 wA[3], wB[3];
        #pragma unroll
        for (int q = 0; q < 3; ++q) {
            wA[q] = *(const f4*)(W4 + c0a * 3 + q * 4);
            wB[q] = *(const f4*)(W4 + c0b * 3 + q * 4);
        }
        #pragma unroll
        for (int s = 0; s < 7; ++s)
            #pragma unroll
            for (int k = 0; k < 4; ++k)
                #pragma unroll
                for (int m = 0; m < 3; ++m) {
                    const int idx = k * 3 + m;
                    part[s][m] = fmaf(h0[s][k], wA[idx >> 2][idx & 3], part[s][m]);
                    part[s][m] = fmaf(h1[s][k], wB[idx >> 2][idx & 3], part[s][m]);
                }
    }

    // reduce across the 32 lanes of this half (xor offsets stay within half)
    #pragma unroll
    for (int s = 0; s < 7; ++s)
        #pragma unroll
        for (int m = 0; m < 3; ++m) {
            float v = part[s][m];
            #pragma unroll
            for (int off = 16; off > 0; off >>= 1) v += __shfl_xor(v, off);
            part[s][m] = v;
        }

    // ---- physics (all lanes of the half redundantly; la==0 accumulates) ----
    const float V0 = part[0][0] + b4[0];
    const float V1 = part[0][1] + b4[1];
    const float V2 = part[0][2] + b4[2];
    const float J00 = part[1][0], J01 = part[2][0], J0t = part[3][0];
    const float J10 = part[1][1], J11 = part[2][1];
    const float J20 = part[1][2], J21 = part[2][2];
    const float H000 = part[4][0], H011 = part[6][0];
    const float H100 = part[4][1], H101 = part[5][1], H111 = part[6][1];
    const float H200 = part[4][2], H201 = part[5][2], H211 = part[6][2];

    const float phi = 1.f / (1.f + expf(-V0));
    const float om  = 1.f - phi;
    const float sp  = phi * om;                  // sigmoid'
    const float spp = sp * (1.f - 2.f * phi);    // sigmoid''
    const float phx0 = sp * J00, phx1 = sp * J01, dphidt = sp * J0t;
    const float lap = spp * (J00 * J00 + J01 * J01) + sp * (H000 + H011);

    const float ld = tt;                          // loading(t) = t
    const float q = x1 * (x1 - 1.f), qp = 2.f * x1 - 1.f;   // q'' = 2

    const float ux0 = q * J10 * ld * (1.f / 3.f);
    const float ux1 = (qp * V1 + q * J11) * ld * (1.f / 3.f);
    const float uy0 = q * J20 * ld;
    const float uy1 = (qp * V2 + q * J21) * ld + ld;

    const float e00 = ux0, e11 = uy1, e01 = 0.5f * (ux1 + uy0);
    const float tr = e00 + e11;

    const float ux_00 = q * H100 * ld * (1.f / 3.f);
    const float ux_01 = (qp * J10 + q * H101) * ld * (1.f / 3.f);
    const float ux_11 = (2.f * V1 + 2.f * qp * J11 + q * H111) * ld * (1.f / 3.f);
    const float uy_00 = q * H200 * ld;
    const float uy_01 = (qp * J20 + q * H201) * ld;
    const float uy_11 = (2.f * V2 + 2.f * qp * J21 + q * H211) * ld;

    const float de00_0 = ux_00, de00_1 = ux_01;
    const float de11_0 = uy_01, de11_1 = uy_11;
    const float de01_0 = 0.5f * (ux_01 + uy_00), de01_1 = 0.5f * (ux_11 + uy_01);
    const float dtr_0 = de00_0 + de11_0, dtr_1 = de00_1 + de11_1;

    const float kk = 2.f;                         // LAMBDA + 2*MU/DIM
    const float rtr = fmaxf(tr, 0.f), rntr = fmaxf(-tr, 0.f);
    const float Hp = (tr > 0.f) ? 1.f : 0.f, Hn = (tr < 0.f) ? 1.f : 0.f;

    const float dv = 0.5f * (e00 - e11);
    const float sp00 = kk * rtr + 2.f * dv;
    const float sp11 = kk * rtr - 2.f * dv;
    const float sp01 = 2.f * e01;
    const float snd  = -kk * rntr;                // sigma_neg diagonal

    const float dsp00_0 = kk * Hp * dtr_0 + 2.f * (de00_0 - 0.5f * dtr_0);
    const float dsp01_0 = 2.f * de01_0;
    const float dsp01_1 = 2.f * de01_1;
    const float dsp11_1 = kk * Hp * dtr_1 + 2.f * (de11_1 - 0.5f * dtr_1);
    const float dsn_0 = kk * Hn * dtr_0, dsn_1 = kk * Hn * dtr_1;

    const float c  = om * om, g = c + 1e-6f;
    const float dc0 = -2.f * om * phx0, dc1 = -2.f * om * phx1;
    const float gpc = g + c, cg = c * g;

    const float res0 = dc0 * gpc * sp00 + cg * dsp00_0 + dc0 * snd + c * dsn_0
                     + dc1 * gpc * sp01 + cg * dsp01_1;
    const float res1 = dc0 * gpc * sp01 + cg * dsp01_0
                     + dc1 * gpc * sp11 + cg * dsp11_1 + dc1 * snd + c * dsn_1;

    const float psip = rtr * rtr + 0.5f * (e00 - e11) * (e00 - e11) + 2.f * e01 * e01;
    const float psin = rntr * rntr;

    const float GCc = 0.0027f, LL = 0.02f;
    const float pf = GCc * (phi / LL - LL * lap) - 2.f * om * psip;
    const bool maskp = (fabsf(dphidt) <= 1e-3f) && (fabsf(phi - 1.f) > 1e-3f);
    const bool maskn = fabsf(phi - 1.f) <= 1e-3f;
    const float respf = maskp ? fmaxf(-pf, 0.f) : (maskn ? fmaxf(pf, 0.f) : pf);

    const float rese = om * 2.f * psip + psin
                     + GCc * (phi * phi / (2.f * LL)
                              + 0.5f * LL * (phx0 * phx0 + phx1 * phx1));
    const float irr = fmaxf(-dphidt, 0.f);

    if (la == 0) {
        float* bin = bins + (blockIdx.x & (NBINS - 1)) * 8;
        atomicAdd(bin + 0, res0 * res0);
        atomicAdd(bin + 1, res1 * res1);
        atomicAdd(bin + 2, respf * respf);
        atomicAdd(bin + 3, rese);
        atomicAdd(bin + 4, irr);
    }
}

// ---------------------------------------------------------------------------
// Finalize: combine bins into the 4 losses
// ---------------------------------------------------------------------------
__global__ void pinn_finalize(const float* __restrict__ bins, float* __restrict__ out)
{
    if (threadIdx.x == 0 && blockIdx.x == 0) {
        float S[5] = {0.f, 0.f, 0.f, 0.f, 0.f};
        for (int b = 0; b < NBINS; ++b)
            for (int k = 0; k < 5; ++k) S[k] += bins[b * 8 + k];
        const float inv_n = 1.f / (float)N_PTS;
        const float mse0 = S[0] * inv_n, mse1 = S[1] * inv_n;
        const float wm = 0.5f * (mse0 + mse1);
        out[0] = wm * mse0 / (mse0 + 1e-6f) + wm * mse1 / (mse1 + 1e-6f);
        out[1] = S[2] * inv_n;
        out[2] = logf(S[3]);
        out[3] = S[4] * inv_n;
    }
}

// ---------------------------------------------------------------------------
extern "C" void kernel_launch(void* const* d_in, const int* in_sizes, int n_in,
                              void* d_out, int out_size, void* d_ws, size_t ws_size,
                              hipStream_t stream)
{
    const float *W[5], *b[5];
    if (in_sizes[1] == HIDDEN) {
        // dict order: W0,b0,W1,b1,...
        for (int i = 0; i < 5; ++i) {
            W[i] = (const float*)d_in[2 * i];
            b[i] = (const float*)d_in[2 * i + 1];
        }
    } else {
        // signature order: W0..W4, b0..b4
        for (int i = 0; i < 5; ++i) {
            W[i] = (const float*)d_in[i];
            b[i] = (const float*)d_in[5 + i];
        }
    }
    const float* x = (const float*)d_in[10];
    const float* t = (const float*)d_in[11];
    float* bins = (float*)d_ws;

    hipMemsetAsync(bins, 0, NBINS * 8 * sizeof(float), stream);
    pinn_main<<<NBLK, THREADS, 0, stream>>>(W[0], b[0], W[1], b[1], W[2], b[2],
                                            W[3], b[3], W[4], b[4], x, t, bins);
    pinn_finalize<<<1, 64, 0, stream>>>(bins, (float*)d_out);
}

// Round 5
// 165.857 us; speedup vs baseline: 2.9946x; 2.4214x over previous
//
#include <hip/hip_runtime.h>
#include <math.h>

#define N_PTS 8192
#define HIDDEN 256
#define PPB 8                   // points per block
#define THREADS 256             // 4 waves
#define NBLK (N_PTS / PPB)      // 1024
#define NBINS 64
#define MROWS 56                // 7 streams x 8 points
#define LDA 264                 // LDS row stride in elements (shorts or f32)
#define BP_OFF 4096             // byte offset of packed W in d_ws

typedef float f32x4 __attribute__((ext_vector_type(4)));
typedef short s8v  __attribute__((ext_vector_type(8)));

__device__ __forceinline__ unsigned short bf16_rne(float x) {
    unsigned int u = __float_as_uint(x);
    return (unsigned short)((u + 0x7FFFu + ((u >> 16) & 1u)) >> 16);
}
__device__ __forceinline__ float bf16f(unsigned short h) {
    return __uint_as_float(((unsigned int)h) << 16);
}

// ---------------------------------------------------------------------------
// Pack W1..W3 (f32 [256][256], row=k, col=n) into MFMA B-frag order, split
// into hi/lo bf16.  Frag convention (must match main kernel's A-side):
//   lane l supplies B[k = kc*32 + (l>>4)*8 + i][n = nt*16 + (l&15)], i=0..7.
// Layout: Bp[((l*2+part)*8+kc)*16+nt)*64+lane)*8 + i]  (shorts)
// ---------------------------------------------------------------------------
__global__ void pinn_pack(const float* __restrict__ W1, const float* __restrict__ W2,
                          const float* __restrict__ W3, unsigned short* __restrict__ Bp)
{
    const int id = blockIdx.x * 256 + threadIdx.x;   // 0..24575
    const int lane = id & 63;
    const int nt   = (id >> 6) & 15;
    const int kc   = (id >> 10) & 7;
    const int l    = id >> 13;                        // 0..2
    const float* W = (l == 0) ? W1 : ((l == 1) ? W2 : W3);
    const int n  = nt * 16 + (lane & 15);
    const int k0 = kc * 32 + (lane >> 4) * 8;
    unsigned short hi[8], lo[8];
    #pragma unroll
    for (int i = 0; i < 8; ++i) {
        const float x = W[(size_t)(k0 + i) * HIDDEN + n];
        const unsigned short h = bf16_rne(x);
        hi[i] = h;
        lo[i] = bf16_rne(x - bf16f(h));
    }
    const size_t bh = ((((size_t)(l * 2 + 0) * 8 + kc) * 16 + nt) * 64 + lane) * 8;
    const size_t bl = ((((size_t)(l * 2 + 1) * 8 + kc) * 16 + nt) * 64 + lane) * 8;
    *(s8v*)&Bp[bh] = *(const s8v*)hi;
    *(s8v*)&Bp[bl] = *(const s8v*)lo;
}

// ---------------------------------------------------------------------------
// Main: second-order forward-mode MLP via split-bf16 MFMA + physics.
// Streams (M rows, r = 8*s + p): 0=val 1=dx0 2=dx1 3=dt 4=dxx 5=dxy 6=dyy
// ---------------------------------------------------------------------------
__global__ __launch_bounds__(THREADS, 2)
void pinn_main(const float* __restrict__ W0, const float* __restrict__ b0,
               const float* __restrict__ b1, const float* __restrict__ b2,
               const float* __restrict__ b3,
               const float* __restrict__ W4, const float* __restrict__ b4,
               const float* __restrict__ xin, const float* __restrict__ tin,
               const unsigned short* __restrict__ Bp,
               float* __restrict__ bins)
{
    // Union: during matmul  -> Ah (bf16 hi) [56][264] + Al (bf16 lo) [56][264]
    //        at boundaries  -> Zf (f32)     [56][264]
    __shared__ __align__(16) unsigned char LB[MROWS * LDA * 4];   // 59136 B
    short* __restrict__ AhS = (short*)LB;
    short* __restrict__ AlS = (short*)(LB + MROWS * LDA * 2);
    float* __restrict__ Zf  = (float*)LB;

    const int tid  = threadIdx.x;
    const int lane = tid & 63;
    const int w    = tid >> 6;          // wave 0..3
    const int c    = lane & 15;
    const int g    = lane >> 4;
    const int t    = tid;               // column owned in boundary phases
    const int pt0  = blockIdx.x * PPB;

    // ---- layer 0 (3 -> 256): thread t = column t, loop over the 8 points ----
    {
        const float w0 = W0[t], w1 = W0[HIDDEN + t], w2 = W0[2 * HIDDEN + t];
        const float bb = b0[t];
        for (int p = 0; p < PPB; ++p) {
            const float x0 = xin[(pt0 + p) * 2 + 0];
            const float x1 = xin[(pt0 + p) * 2 + 1];
            const float tt = tin[pt0 + p];
            const float z  = fmaf(x0, w0, fmaf(x1, w1, fmaf(tt, w2, bb)));
            const float a  = tanhf(z);
            const float st = 1.f - a * a;
            const float m2 = -2.f * a * st;
            float v[7];
            v[0] = a;
            v[1] = st * w0; v[2] = st * w1; v[3] = st * w2;
            v[4] = m2 * w0 * w0; v[5] = m2 * w0 * w1; v[6] = m2 * w1 * w1;
            #pragma unroll
            for (int s = 0; s < 7; ++s) {
                const int r = 8 * s + p;
                const unsigned short h = bf16_rne(v[s]);
                AhS[r * LDA + t] = (short)h;
                AlS[r * LDA + t] = (short)bf16_rne(v[s] - bf16f(h));
            }
        }
    }
    __syncthreads();

    // per-thread A-frag row offsets (clamped so pad rows stay in-bounds)
    int aoff[4];
    #pragma unroll
    for (int mt = 0; mt < 4; ++mt) {
        int arow = mt * 16 + c;
        if (arow > MROWS - 1) arow = MROWS - 1;      // pad rows: dup, unused
        aoff[mt] = arow * LDA + g * 8;
    }

    // ---- hidden layers: matmul (split-bf16 MFMA) + boundary nonlinearity ----
    for (int l = 0; l < 3; ++l) {
        f32x4 acc[4][4];
        #pragma unroll
        for (int mt = 0; mt < 4; ++mt)
            #pragma unroll
            for (int nn = 0; nn < 4; ++nn) acc[mt][nn] = (f32x4)0.f;

        const size_t lbase = (size_t)l * 2 * 8 * 16 * 64 * 8;
        for (int kc = 0; kc < 8; ++kc) {
            s8v ah[4], al[4];
            #pragma unroll
            for (int mt = 0; mt < 4; ++mt) {
                ah[mt] = *(const s8v*)&AhS[aoff[mt] + kc * 32];
                al[mt] = *(const s8v*)&AlS[aoff[mt] + kc * 32];
            }
            s8v bh[4], bl[4];
            #pragma unroll
            for (int nn = 0; nn < 4; ++nn) {
                const int nt = w * 4 + nn;
                const size_t oh = lbase + (((size_t)kc * 16 + nt) * 64 + lane) * 8;
                const size_t ol = oh + (size_t)8 * 16 * 64 * 8;
                bh[nn] = *(const s8v*)&Bp[oh];
                bl[nn] = *(const s8v*)&Bp[ol];
            }
            #pragma unroll
            for (int mt = 0; mt < 4; ++mt)
                #pragma unroll
                for (int nn = 0; nn < 4; ++nn) {
                    acc[mt][nn] = __builtin_amdgcn_mfma_f32_16x16x32_bf16(ah[mt], bh[nn], acc[mt][nn], 0, 0, 0);
                    acc[mt][nn] = __builtin_amdgcn_mfma_f32_16x16x32_bf16(ah[mt], bl[nn], acc[mt][nn], 0, 0, 0);
                    acc[mt][nn] = __builtin_amdgcn_mfma_f32_16x16x32_bf16(al[mt], bh[nn], acc[mt][nn], 0, 0, 0);
                }
        }
        __syncthreads();                 // all A reads done -> safe to clobber

        // write pre-activations Z (f32) over the A region
        #pragma unroll
        for (int mt = 0; mt < 4; ++mt)
            #pragma unroll
            for (int nn = 0; nn < 4; ++nn)
                #pragma unroll
                for (int r = 0; r < 4; ++r) {
                    const int row = mt * 16 + g * 4 + r;
                    if (row < MROWS)
                        Zf[row * LDA + w * 64 + nn * 16 + c] = acc[mt][nn][r];
                }
        __syncthreads();

        // pull this thread's column into registers
        float zr[MROWS];
        #pragma unroll
        for (int r = 0; r < MROWS; ++r) zr[r] = Zf[r * LDA + t];
        __syncthreads();                 // reads done -> safe to overwrite

        const float bias = ((l == 0) ? b1 : (l == 1) ? b2 : b3)[t];
        for (int p = 0; p < PPB; ++p) {
            const float zv = zr[p] + bias;
            const float a  = tanhf(zv);
            const float st = 1.f - a * a;
            const float m2 = -2.f * a * st;
            const float z1 = zr[8 + p],  z2 = zr[16 + p], z3 = zr[24 + p];
            const float z4 = zr[32 + p], z5 = zr[40 + p], z6 = zr[48 + p];
            float v[7];
            v[0] = a;
            v[1] = st * z1; v[2] = st * z2; v[3] = st * z3;
            v[4] = fmaf(m2 * z1, z1, st * z4);
            v[5] = fmaf(m2 * z1, z2, st * z5);
            v[6] = fmaf(m2 * z2, z2, st * z6);
            if (l < 2) {
                #pragma unroll
                for (int s = 0; s < 7; ++s) {
                    const int r = 8 * s + p;
                    const unsigned short h = bf16_rne(v[s]);
                    AhS[r * LDA + t] = (short)h;
                    AlS[r * LDA + t] = (short)bf16_rne(v[s] - bf16f(h));
                }
            } else {
                #pragma unroll
                for (int s = 0; s < 7; ++s)
                    Zf[(8 * s + p) * LDA + t] = v[s];   // final H, f32
            }
        }
        __syncthreads();
    }

    // ---- final layer (256 -> 3): half-wave per point, k strided by lane ----
    const int h  = (lane >> 5);
    const int la = lane & 31;
    const int p  = w * 2 + h;

    float part[7][3];
    #pragma unroll
    for (int s = 0; s < 7; ++s)
        #pragma unroll
        for (int m = 0; m < 3; ++m) part[s][m] = 0.f;

    #pragma unroll
    for (int i = 0; i < 8; ++i) {
        const int k = la + 32 * i;
        const float w40 = W4[k * 3 + 0], w41 = W4[k * 3 + 1], w42 = W4[k * 3 + 2];
        #pragma unroll
        for (int s = 0; s < 7; ++s) {
            const float hk = Zf[(8 * s + p) * LDA + k];
            part[s][0] = fmaf(hk, w40, part[s][0]);
            part[s][1] = fmaf(hk, w41, part[s][1]);
            part[s][2] = fmaf(hk, w42, part[s][2]);
        }
    }
    #pragma unroll
    for (int s = 0; s < 7; ++s)
        #pragma unroll
        for (int m = 0; m < 3; ++m) {
            float v = part[s][m];
            #pragma unroll
            for (int off = 16; off > 0; off >>= 1) v += __shfl_xor(v, off);
            part[s][m] = v;
        }

    // ---- physics (identical math to r4, verified) ----
    const float x0 = xin[(pt0 + p) * 2 + 0];
    const float x1 = xin[(pt0 + p) * 2 + 1];
    const float tt = tin[pt0 + p];

    const float V0 = part[0][0] + b4[0];
    const float V1 = part[0][1] + b4[1];
    const float V2 = part[0][2] + b4[2];
    const float J00 = part[1][0], J01 = part[2][0], J0t = part[3][0];
    const float J10 = part[1][1], J11 = part[2][1];
    const float J20 = part[1][2], J21 = part[2][2];
    const float H000 = part[4][0], H011 = part[6][0];
    const float H100 = part[4][1], H101 = part[5][1], H111 = part[6][1];
    const float H200 = part[4][2], H201 = part[5][2], H211 = part[6][2];

    const float phi = 1.f / (1.f + expf(-V0));
    const float om  = 1.f - phi;
    const float sp  = phi * om;
    const float spp = sp * (1.f - 2.f * phi);
    const float phx0 = sp * J00, phx1 = sp * J01, dphidt = sp * J0t;
    const float lap = spp * (J00 * J00 + J01 * J01) + sp * (H000 + H011);

    const float ld = tt;
    const float q = x1 * (x1 - 1.f), qp = 2.f * x1 - 1.f;

    const float ux0 = q * J10 * ld * (1.f / 3.f);
    const float ux1 = (qp * V1 + q * J11) * ld * (1.f / 3.f);
    const float uy0 = q * J20 * ld;
    const float uy1 = (qp * V2 + q * J21) * ld + ld;

    const float e00 = ux0, e11 = uy1, e01 = 0.5f * (ux1 + uy0);
    const float tr = e00 + e11;

    const float ux_00 = q * H100 * ld * (1.f / 3.f);
    const float ux_01 = (qp * J10 + q * H101) * ld * (1.f / 3.f);
    const float ux_11 = (2.f * V1 + 2.f * qp * J11 + q * H111) * ld * (1.f / 3.f);
    const float uy_00 = q * H200 * ld;
    const float uy_01 = (qp * J20 + q * H201) * ld;
    const float uy_11 = (2.f * V2 + 2.f * qp * J21 + q * H211) * ld;

    const float de00_0 = ux_00, de00_1 = ux_01;
    const float de11_0 = uy_01, de11_1 = uy_11;
    const float de01_0 = 0.5f * (ux_01 + uy_00), de01_1 = 0.5f * (ux_11 + uy_01);
    const float dtr_0 = de00_0 + de11_0, dtr_1 = de00_1 + de11_1;

    const float kk = 2.f;
    const float rtr = fmaxf(tr, 0.f), rntr = fmaxf(-tr, 0.f);
    const float Hp = (tr > 0.f) ? 1.f : 0.f, Hn = (tr < 0.f) ? 1.f : 0.f;

    const float dv = 0.5f * (e00 - e11);
    const float sp00 = kk * rtr + 2.f * dv;
    const float sp11 = kk * rtr - 2.f * dv;
    const float sp01 = 2.f * e01;
    const float snd  = -kk * rntr;

    const float dsp00_0 = kk * Hp * dtr_0 + 2.f * (de00_0 - 0.5f * dtr_0);
    const float dsp01_0 = 2.f * de01_0;
    const float dsp01_1 = 2.f * de01_1;
    const float dsp11_1 = kk * Hp * dtr_1 + 2.f * (de11_1 - 0.5f * dtr_1);
    const float dsn_0 = kk * Hn * dtr_0, dsn_1 = kk * Hn * dtr_1;

    const float cc  = om * om, gg = cc + 1e-6f;
    const float dc0 = -2.f * om * phx0, dc1 = -2.f * om * phx1;
    const float gpc = gg + cc, cg = cc * gg;

    const float res0 = dc0 * gpc * sp00 + cg * dsp00_0 + dc0 * snd + cc * dsn_0
                     + dc1 * gpc * sp01 + cg * dsp01_1;
    const float res1 = dc0 * gpc * sp01 + cg * dsp01_0
                     + dc1 * gpc * sp11 + cg * dsp11_1 + dc1 * snd + cc * dsn_1;

    const float psip = rtr * rtr + 0.5f * (e00 - e11) * (e00 - e11) + 2.f * e01 * e01;
    const float psin = rntr * rntr;

    const float GCc = 0.0027f, LL = 0.02f;
    const float pf = GCc * (phi / LL - LL * lap) - 2.f * om * psip;
    const bool maskp = (fabsf(dphidt) <= 1e-3f) && (fabsf(phi - 1.f) > 1e-3f);
    const bool maskn = fabsf(phi - 1.f) <= 1e-3f;
    const float respf = maskp ? fmaxf(-pf, 0.f) : (maskn ? fmaxf(pf, 0.f) : pf);

    const float rese = om * 2.f * psip + psin
                     + GCc * (phi * phi / (2.f * LL)
                              + 0.5f * LL * (phx0 * phx0 + phx1 * phx1));
    const float irr = fmaxf(-dphidt, 0.f);

    if (la == 0) {
        float* bin = bins + (blockIdx.x & (NBINS - 1)) * 8;
        atomicAdd(bin + 0, res0 * res0);
        atomicAdd(bin + 1, res1 * res1);
        atomicAdd(bin + 2, respf * respf);
        atomicAdd(bin + 3, rese);
        atomicAdd(bin + 4, irr);
    }
}

// ---------------------------------------------------------------------------
__global__ void pinn_finalize(const float* __restrict__ bins, float* __restrict__ out)
{
    if (threadIdx.x == 0 && blockIdx.x == 0) {
        float S[5] = {0.f, 0.f, 0.f, 0.f, 0.f};
        for (int b = 0; b < NBINS; ++b)
            for (int k = 0; k < 5; ++k) S[k] += bins[b * 8 + k];
        const float inv_n = 1.f / (float)N_PTS;
        const float mse0 = S[0] * inv_n, mse1 = S[1] * inv_n;
        const float wm = 0.5f * (mse0 + mse1);
        out[0] = wm * mse0 / (mse0 + 1e-6f) + wm * mse1 / (mse1 + 1e-6f);
        out[1] = S[2] * inv_n;
        out[2] = logf(S[3]);
        out[3] = S[4] * inv_n;
    }
}

// ---------------------------------------------------------------------------
extern "C" void kernel_launch(void* const* d_in, const int* in_sizes, int n_in,
                              void* d_out, int out_size, void* d_ws, size_t ws_size,
                              hipStream_t stream)
{
    const float *W[5], *b[5];
    if (in_sizes[1] == HIDDEN) {
        for (int i = 0; i < 5; ++i) {           // dict order W0,b0,W1,b1,...
            W[i] = (const float*)d_in[2 * i];
            b[i] = (const float*)d_in[2 * i + 1];
        }
    } else {
        for (int i = 0; i < 5; ++i) {           // signature order W0..W4, b0..b4
            W[i] = (const float*)d_in[i];
            b[i] = (const float*)d_in[5 + i];
        }
    }
    const float* x = (const float*)d_in[10];
    const float* t = (const float*)d_in[11];
    float* bins = (float*)d_ws;
    unsigned short* Bp = (unsigned short*)((char*)d_ws + BP_OFF);

    hipMemsetAsync(bins, 0, NBINS * 8 * sizeof(float), stream);
    pinn_pack<<<96, 256, 0, stream>>>(W[1], W[2], W[3], Bp);
    pinn_main<<<NBLK, THREADS, 0, stream>>>(W[0], b[0], b[1], b[2], b[3],
                                            W[4], b[4], x, t, Bp, bins);
    pinn_finalize<<<1, 64, 0, stream>>>(bins, (float*)d_out);
}

// Round 6
// 161.625 us; speedup vs baseline: 3.0730x; 1.0262x over previous
//
#include <hip/hip_runtime.h>
#include <math.h>

#define N_PTS 8192
#define HIDDEN 256
#define PPB 8                   // points per block
#define THREADS 256             // 4 waves
#define NBLK (N_PTS / PPB)      // 1024
#define NBINS 64
#define MROWS 56                // 7 streams x 8 points
#define LDA 264                 // A (bf16) row stride in shorts; 264*2B=528B/row
#define LDZ 260                 // Zf (f32) row stride in floats; rows 4 apart -> +16 banks (2-way, free)
#define BP_OFF 4096             // byte offset of packed W in d_ws

typedef float f32x4 __attribute__((ext_vector_type(4)));
typedef short s8v  __attribute__((ext_vector_type(8)));
typedef short s4v  __attribute__((ext_vector_type(4)));

__device__ __forceinline__ unsigned short bf16_rne(float x) {
    unsigned int u = __float_as_uint(x);
    return (unsigned short)((u + 0x7FFFu + ((u >> 16) & 1u)) >> 16);
}
__device__ __forceinline__ float bf16f(unsigned short h) {
    return __uint_as_float(((unsigned int)h) << 16);
}

// ---------------------------------------------------------------------------
// Pack W1..W3 (f32 [256][256], row=k, col=n) into MFMA B-frag order, split
// into hi/lo bf16.  Frag convention (must match main kernel's A-side):
//   lane l supplies B[k = kc*32 + (l>>4)*8 + i][n = nt*16 + (l&15)], i=0..7.
// Layout: Bp[(((l*2+part)*8+kc)*16+nt)*64+lane)*8 + i]  (shorts)
// Block 0 also zeroes the bins (replaces a separate memset dispatch).
// ---------------------------------------------------------------------------
__global__ void pinn_pack(const float* __restrict__ W1, const float* __restrict__ W2,
                          const float* __restrict__ W3, unsigned short* __restrict__ Bp,
                          float* __restrict__ bins)
{
    if (blockIdx.x == 0) {
        bins[threadIdx.x] = 0.f;
        bins[threadIdx.x + 256] = 0.f;
    }
    const int id = blockIdx.x * 256 + threadIdx.x;   // 0..24575
    const int lane = id & 63;
    const int nt   = (id >> 6) & 15;
    const int kc   = (id >> 10) & 7;
    const int l    = id >> 13;                        // 0..2
    const float* W = (l == 0) ? W1 : ((l == 1) ? W2 : W3);
    const int n  = nt * 16 + (lane & 15);
    const int k0 = kc * 32 + (lane >> 4) * 8;
    unsigned short hi[8], lo[8];
    #pragma unroll
    for (int i = 0; i < 8; ++i) {
        const float x = W[(size_t)(k0 + i) * HIDDEN + n];
        const unsigned short h = bf16_rne(x);
        hi[i] = h;
        lo[i] = bf16_rne(x - bf16f(h));
    }
    const size_t bh = ((((size_t)(l * 2 + 0) * 8 + kc) * 16 + nt) * 64 + lane) * 8;
    const size_t bl = ((((size_t)(l * 2 + 1) * 8 + kc) * 16 + nt) * 64 + lane) * 8;
    *(s8v*)&Bp[bh] = *(const s8v*)hi;
    *(s8v*)&Bp[bl] = *(const s8v*)lo;
}

// ---------------------------------------------------------------------------
// Main: second-order forward-mode MLP via split-bf16 MFMA + physics.
// Streams (M rows, r = 8*s + p): 0=val 1=dx0 2=dx1 3=dt 4=dxx 5=dxy 6=dyy
// Boundary phases: thread = (q = tid&63 -> cols q*4..q*4+3, pp = tid>>6 ->
// points {pp, pp+4}) so all LDS traffic is b128 reads / b64 writes.
// ---------------------------------------------------------------------------
__global__ __launch_bounds__(THREADS, 2)
void pinn_main(const float* __restrict__ W0, const float* __restrict__ b0,
               const float* __restrict__ b1, const float* __restrict__ b2,
               const float* __restrict__ b3,
               const float* __restrict__ W4, const float* __restrict__ b4,
               const float* __restrict__ xin, const float* __restrict__ tin,
               const unsigned short* __restrict__ Bp,
               float* __restrict__ bins)
{
    // Union: during matmul  -> Ah (bf16 hi) [56][LDA] + Al (bf16 lo) [56][LDA]
    //        at boundaries  -> Zf (f32)     [56][LDZ]
    __shared__ __align__(16) unsigned char LB[MROWS * LDA * 4];   // 59136 B
    short* __restrict__ AhS = (short*)LB;
    short* __restrict__ AlS = (short*)(LB + MROWS * LDA * 2);
    float* __restrict__ Zf  = (float*)LB;

    const int tid  = threadIdx.x;
    const int lane = tid & 63;
    const int w    = tid >> 6;          // wave 0..3
    const int c    = lane & 15;
    const int g    = lane >> 4;
    const int q    = tid & 63;          // column group in boundary phases
    const int pp   = tid >> 6;          // point pair base
    const int pt0  = blockIdx.x * PPB;

    // ---- layer 0 (3 -> 256): thread (q, pp) covers cols q*4.., points pp,pp+4
    {
        const f32x4 w0 = *(const f32x4*)(W0 + q * 4);
        const f32x4 w1 = *(const f32x4*)(W0 + HIDDEN + q * 4);
        const f32x4 w2 = *(const f32x4*)(W0 + 2 * HIDDEN + q * 4);
        const f32x4 bb = *(const f32x4*)(b0 + q * 4);
        #pragma unroll
        for (int p2 = 0; p2 < 2; ++p2) {
            const int p = pp + 4 * p2;
            const float x0 = xin[(pt0 + p) * 2 + 0];
            const float x1 = xin[(pt0 + p) * 2 + 1];
            const float tt = tin[pt0 + p];
            s4v hi[7], lo[7];
            #pragma unroll
            for (int jj = 0; jj < 4; ++jj) {
                const float z  = fmaf(x0, w0[jj], fmaf(x1, w1[jj], fmaf(tt, w2[jj], bb[jj])));
                const float a  = tanhf(z);
                const float st = 1.f - a * a;
                const float m2 = -2.f * a * st;
                float v[7];
                v[0] = a;
                v[1] = st * w0[jj]; v[2] = st * w1[jj]; v[3] = st * w2[jj];
                v[4] = m2 * w0[jj] * w0[jj];
                v[5] = m2 * w0[jj] * w1[jj];
                v[6] = m2 * w1[jj] * w1[jj];
                #pragma unroll
                for (int s = 0; s < 7; ++s) {
                    const unsigned short h = bf16_rne(v[s]);
                    hi[s][jj] = (short)h;
                    lo[s][jj] = (short)bf16_rne(v[s] - bf16f(h));
                }
            }
            #pragma unroll
            for (int s = 0; s < 7; ++s) {
                const int r = 8 * s + p;
                *(s4v*)&AhS[r * LDA + q * 4] = hi[s];
                *(s4v*)&AlS[r * LDA + q * 4] = lo[s];
            }
        }
    }
    __syncthreads();

    // per-thread A-frag row offsets (clamped so pad rows stay in-bounds)
    int aoff[4];
    #pragma unroll
    for (int mt = 0; mt < 4; ++mt) {
        int arow = mt * 16 + c;
        if (arow > MROWS - 1) arow = MROWS - 1;      // pad rows: dup, unused
        aoff[mt] = arow * LDA + g * 8;
    }

    // ---- hidden layers: matmul (split-bf16 MFMA) + boundary nonlinearity ----
    for (int l = 0; l < 3; ++l) {
        f32x4 acc[4][4];
        #pragma unroll
        for (int mt = 0; mt < 4; ++mt)
            #pragma unroll
            for (int nn = 0; nn < 4; ++nn) acc[mt][nn] = (f32x4)0.f;

        const size_t lbase = (size_t)l * 2 * 8 * 16 * 64 * 8;
        #pragma unroll
        for (int kc = 0; kc < 8; ++kc) {
            s8v ah[4], al[4];
            #pragma unroll
            for (int mt = 0; mt < 4; ++mt) {
                ah[mt] = *(const s8v*)&AhS[aoff[mt] + kc * 32];
                al[mt] = *(const s8v*)&AlS[aoff[mt] + kc * 32];
            }
            s8v bh[4], bl[4];
            #pragma unroll
            for (int nn = 0; nn < 4; ++nn) {
                const int nt = w * 4 + nn;
                const size_t oh = lbase + (((size_t)kc * 16 + nt) * 64 + lane) * 8;
                const size_t ol = oh + (size_t)8 * 16 * 64 * 8;
                bh[nn] = *(const s8v*)&Bp[oh];
                bl[nn] = *(const s8v*)&Bp[ol];
            }
            #pragma unroll
            for (int mt = 0; mt < 4; ++mt)
                #pragma unroll
                for (int nn = 0; nn < 4; ++nn) {
                    acc[mt][nn] = __builtin_amdgcn_mfma_f32_16x16x32_bf16(ah[mt], bh[nn], acc[mt][nn], 0, 0, 0);
                    acc[mt][nn] = __builtin_amdgcn_mfma_f32_16x16x32_bf16(ah[mt], bl[nn], acc[mt][nn], 0, 0, 0);
                    acc[mt][nn] = __builtin_amdgcn_mfma_f32_16x16x32_bf16(al[mt], bh[nn], acc[mt][nn], 0, 0, 0);
                }
        }
        __syncthreads();                 // all A reads done -> safe to clobber (Zf aliases A)

        // C-store: acc -> Zf (f32, stride LDZ: rows 4 apart land +16 banks)
        #pragma unroll
        for (int mt = 0; mt < 4; ++mt)
            #pragma unroll
            for (int nn = 0; nn < 4; ++nn)
                #pragma unroll
                for (int r = 0; r < 4; ++r) {
                    const int row = mt * 16 + g * 4 + r;
                    if (row < MROWS)
                        Zf[row * LDZ + w * 64 + nn * 16 + c] = acc[mt][nn][r];
                }
        __syncthreads();

        // pull this thread's 2 points x 4 cols x 7 streams into regs (b128)
        f32x4 z[2][7];
        #pragma unroll
        for (int p2 = 0; p2 < 2; ++p2) {
            const int p = pp + 4 * p2;
            #pragma unroll
            for (int s = 0; s < 7; ++s)
                z[p2][s] = *(const f32x4*)&Zf[(8 * s + p) * LDZ + q * 4];
        }
        __syncthreads();                 // reads done -> safe to overwrite

        const float* bias = (l == 0) ? b1 : (l == 1) ? b2 : b3;
        const f32x4 bb = *(const f32x4*)(bias + q * 4);
        #pragma unroll
        for (int p2 = 0; p2 < 2; ++p2) {
            const int p = pp + 4 * p2;
            s4v hi[7], lo[7];
            f32x4 vf[7];
            #pragma unroll
            for (int jj = 0; jj < 4; ++jj) {
                const float zv = z[p2][0][jj] + bb[jj];
                const float a  = tanhf(zv);
                const float st = 1.f - a * a;
                const float m2 = -2.f * a * st;
                const float z1 = z[p2][1][jj], z2 = z[p2][2][jj], z3 = z[p2][3][jj];
                float v[7];
                v[0] = a;
                v[1] = st * z1; v[2] = st * z2; v[3] = st * z3;
                v[4] = fmaf(m2 * z1, z1, st * z[p2][4][jj]);
                v[5] = fmaf(m2 * z1, z2, st * z[p2][5][jj]);
                v[6] = fmaf(m2 * z2, z2, st * z[p2][6][jj]);
                if (l < 2) {
                    #pragma unroll
                    for (int s = 0; s < 7; ++s) {
                        const unsigned short h = bf16_rne(v[s]);
                        hi[s][jj] = (short)h;
                        lo[s][jj] = (short)bf16_rne(v[s] - bf16f(h));
                    }
                } else {
                    #pragma unroll
                    for (int s = 0; s < 7; ++s) vf[s][jj] = v[s];
                }
            }
            if (l < 2) {
                #pragma unroll
                for (int s = 0; s < 7; ++s) {
                    const int r = 8 * s + p;
                    *(s4v*)&AhS[r * LDA + q * 4] = hi[s];
                    *(s4v*)&AlS[r * LDA + q * 4] = lo[s];
                }
            } else {
                #pragma unroll
                for (int s = 0; s < 7; ++s)
                    *(f32x4*)&Zf[(8 * s + p) * LDZ + q * 4] = vf[s];   // final H, f32
            }
        }
        __syncthreads();
    }

    // ---- final layer (256 -> 3): half-wave per point, k strided by lane ----
    const int h  = (lane >> 5);
    const int la = lane & 31;
    const int p  = w * 2 + h;

    float part[7][3];
    #pragma unroll
    for (int s = 0; s < 7; ++s)
        #pragma unroll
        for (int m = 0; m < 3; ++m) part[s][m] = 0.f;

    #pragma unroll
    for (int i = 0; i < 8; ++i) {
        const int k = la + 32 * i;
        const float w40 = W4[k * 3 + 0], w41 = W4[k * 3 + 1], w42 = W4[k * 3 + 2];
        #pragma unroll
        for (int s = 0; s < 7; ++s) {
            const float hk = Zf[(8 * s + p) * LDZ + k];
            part[s][0] = fmaf(hk, w40, part[s][0]);
            part[s][1] = fmaf(hk, w41, part[s][1]);
            part[s][2] = fmaf(hk, w42, part[s][2]);
        }
    }
    #pragma unroll
    for (int s = 0; s < 7; ++s)
        #pragma unroll
        for (int m = 0; m < 3; ++m) {
            float v = part[s][m];
            #pragma unroll
            for (int off = 16; off > 0; off >>= 1) v += __shfl_xor(v, off);
            part[s][m] = v;
        }

    // ---- physics (identical math to r5, verified) ----
    const float x0 = xin[(pt0 + p) * 2 + 0];
    const float x1 = xin[(pt0 + p) * 2 + 1];
    const float tt = tin[pt0 + p];

    const float V0 = part[0][0] + b4[0];
    const float V1 = part[0][1] + b4[1];
    const float V2 = part[0][2] + b4[2];
    const float J00 = part[1][0], J01 = part[2][0], J0t = part[3][0];
    const float J10 = part[1][1], J11 = part[2][1];
    const float J20 = part[1][2], J21 = part[2][2];
    const float H000 = part[4][0], H011 = part[6][0];
    const float H100 = part[4][1], H101 = part[5][1], H111 = part[6][1];
    const float H200 = part[4][2], H201 = part[5][2], H211 = part[6][2];

    const float phi = 1.f / (1.f + expf(-V0));
    const float om  = 1.f - phi;
    const float sp  = phi * om;
    const float spp = sp * (1.f - 2.f * phi);
    const float phx0 = sp * J00, phx1 = sp * J01, dphidt = sp * J0t;
    const float lap = spp * (J00 * J00 + J01 * J01) + sp * (H000 + H011);

    const float ld = tt;
    const float qq = x1 * (x1 - 1.f), qp = 2.f * x1 - 1.f;

    const float ux0 = qq * J10 * ld * (1.f / 3.f);
    const float ux1 = (qp * V1 + qq * J11) * ld * (1.f / 3.f);
    const float uy0 = qq * J20 * ld;
    const float uy1 = (qp * V2 + qq * J21) * ld + ld;

    const float e00 = ux0, e11 = uy1, e01 = 0.5f * (ux1 + uy0);
    const float tr = e00 + e11;

    const float ux_00 = qq * H100 * ld * (1.f / 3.f);
    const float ux_01 = (qp * J10 + qq * H101) * ld * (1.f / 3.f);
    const float ux_11 = (2.f * V1 + 2.f * qp * J11 + qq * H111) * ld * (1.f / 3.f);
    const float uy_00 = qq * H200 * ld;
    const float uy_01 = (qp * J20 + qq * H201) * ld;
    const float uy_11 = (2.f * V2 + 2.f * qp * J21 + qq * H211) * ld;

    const float de00_0 = ux_00, de00_1 = ux_01;
    const float de11_0 = uy_01, de11_1 = uy_11;
    const float de01_0 = 0.5f * (ux_01 + uy_00), de01_1 = 0.5f * (ux_11 + uy_01);
    const float dtr_0 = de00_0 + de11_0, dtr_1 = de00_1 + de11_1;

    const float kk = 2.f;
    const float rtr = fmaxf(tr, 0.f), rntr = fmaxf(-tr, 0.f);
    const float Hp = (tr > 0.f) ? 1.f : 0.f, Hn = (tr < 0.f) ? 1.f : 0.f;

    const float dv = 0.5f * (e00 - e11);
    const float sp00 = kk * rtr + 2.f * dv;
    const float sp11 = kk * rtr - 2.f * dv;
    const float sp01 = 2.f * e01;
    const float snd  = -kk * rntr;

    const float dsp00_0 = kk * Hp * dtr_0 + 2.f * (de00_0 - 0.5f * dtr_0);
    const float dsp01_0 = 2.f * de01_0;
    const float dsp01_1 = 2.f * de01_1;
    const float dsp11_1 = kk * Hp * dtr_1 + 2.f * (de11_1 - 0.5f * dtr_1);
    const float dsn_0 = kk * Hn * dtr_0, dsn_1 = kk * Hn * dtr_1;

    const float cc  = om * om, gg = cc + 1e-6f;
    const float dc0 = -2.f * om * phx0, dc1 = -2.f * om * phx1;
    const float gpc = gg + cc, cg = cc * gg;

    const float res0 = dc0 * gpc * sp00 + cg * dsp00_0 + dc0 * snd + cc * dsn_0
                     + dc1 * gpc * sp01 + cg * dsp01_1;
    const float res1 = dc0 * gpc * sp01 + cg * dsp01_0
                     + dc1 * gpc * sp11 + cg * dsp11_1 + dc1 * snd + cc * dsn_1;

    const float psip = rtr * rtr + 0.5f * (e00 - e11) * (e00 - e11) + 2.f * e01 * e01;
    const float psin = rntr * rntr;

    const float GCc = 0.0027f, LL = 0.02f;
    const float pf = GCc * (phi / LL - LL * lap) - 2.f * om * psip;
    const bool maskp = (fabsf(dphidt) <= 1e-3f) && (fabsf(phi - 1.f) > 1e-3f);
    const bool maskn = fabsf(phi - 1.f) <= 1e-3f;
    const float respf = maskp ? fmaxf(-pf, 0.f) : (maskn ? fmaxf(pf, 0.f) : pf);

    const float rese = om * 2.f * psip + psin
                     + GCc * (phi * phi / (2.f * LL)
                              + 0.5f * LL * (phx0 * phx0 + phx1 * phx1));
    const float irr = fmaxf(-dphidt, 0.f);

    if (la == 0) {
        float* bin = bins + (blockIdx.x & (NBINS - 1)) * 8;
        atomicAdd(bin + 0, res0 * res0);
        atomicAdd(bin + 1, res1 * res1);
        atomicAdd(bin + 2, respf * respf);
        atomicAdd(bin + 3, rese);
        atomicAdd(bin + 4, irr);
    }
}

// ---------------------------------------------------------------------------
// Finalize: one wave; lane b owns bin b, shuffle-reduce, lane 0 writes.
// ---------------------------------------------------------------------------
__global__ void pinn_finalize(const float* __restrict__ bins, float* __restrict__ out)
{
    const int lane = threadIdx.x;      // 64 threads = 1 wave
    float s0 = bins[lane * 8 + 0];
    float s1 = bins[lane * 8 + 1];
    float s2 = bins[lane * 8 + 2];
    float s3 = bins[lane * 8 + 3];
    float s4 = bins[lane * 8 + 4];
    #pragma unroll
    for (int off = 32; off > 0; off >>= 1) {
        s0 += __shfl_xor(s0, off);
        s1 += __shfl_xor(s1, off);
        s2 += __shfl_xor(s2, off);
        s3 += __shfl_xor(s3, off);
        s4 += __shfl_xor(s4, off);
    }
    if (lane == 0) {
        const float inv_n = 1.f / (float)N_PTS;
        const float mse0 = s0 * inv_n, mse1 = s1 * inv_n;
        const float wm = 0.5f * (mse0 + mse1);
        out[0] = wm * mse0 / (mse0 + 1e-6f) + wm * mse1 / (mse1 + 1e-6f);
        out[1] = s2 * inv_n;
        out[2] = logf(s3);
        out[3] = s4 * inv_n;
    }
}

// ---------------------------------------------------------------------------
extern "C" void kernel_launch(void* const* d_in, const int* in_sizes, int n_in,
                              void* d_out, int out_size, void* d_ws, size_t ws_size,
                              hipStream_t stream)
{
    const float *W[5], *b[5];
    if (in_sizes[1] == HIDDEN) {
        for (int i = 0; i < 5; ++i) {           // dict order W0,b0,W1,b1,...
            W[i] = (const float*)d_in[2 * i];
            b[i] = (const float*)d_in[2 * i + 1];
        }
    } else {
        for (int i = 0; i < 5; ++i) {           // signature order W0..W4, b0..b4
            W[i] = (const float*)d_in[i];
            b[i] = (const float*)d_in[5 + i];
        }
    }
    const float* x = (const float*)d_in[10];
    const float* t = (const float*)d_in[11];
    float* bins = (float*)d_ws;
    unsigned short* Bp = (unsigned short*)((char*)d_ws + BP_OFF);

    pinn_pack<<<96, 256, 0, stream>>>(W[1], W[2], W[3], Bp, bins);
    pinn_main<<<NBLK, THREADS, 0, stream>>>(W[0], b[0], b[1], b[2], b[3],
                                            W[4], b[4], x, t, Bp, bins);
    pinn_finalize<<<1, 64, 0, stream>>>(bins, (float*)d_out);
}

// Round 7
// 155.126 us; speedup vs baseline: 3.2017x; 1.0419x over previous
//
#include <hip/hip_runtime.h>
#include <math.h>

#define N_PTS 8192
#define HIDDEN 256
#define PPB 8                   // points per block
#define THREADS 256             // 4 waves
#define NBLK (N_PTS / PPB)      // 1024
#define NBINS 64
#define LDA 264                 // A row stride in shorts (528 B)
#define AROWS 62                // rows 0..61 stored (62,63 clamped away)
#define LDZ 264                 // final-H f32 row stride
#define BP_OFF 4096             // byte offset of packed W in d_ws

typedef float f32x4 __attribute__((ext_vector_type(4)));
typedef short s8v  __attribute__((ext_vector_type(8)));
typedef short s4v  __attribute__((ext_vector_type(4)));

__device__ __forceinline__ unsigned short bf16_rne(float x) {
    unsigned int u = __float_as_uint(x);
    return (unsigned short)((u + 0x7FFFu + ((u >> 16) & 1u)) >> 16);
}
__device__ __forceinline__ float bf16f(unsigned short h) {
    return __uint_as_float(((unsigned int)h) << 16);
}
// row index of (stream s, point p) in the A/C matrix
__device__ __forceinline__ int rowof(int s, int p) {
    return (s < 6) ? ((s >> 1) * 16 + (p >> 1) * 4 + (p & 1) * 2 + (s & 1))
                   : (48 + (p >> 1) * 4 + (p & 1));
}

// ---------------------------------------------------------------------------
// Pack W1..W3 into MFMA B-frag order with the k-slot permutation:
// slot sigma holds original neuron j = 64*(sigma>>6) + 16*(sigma&3) + ((sigma>>2)&15).
// Lane l supplies B[k = pi(kc*32 + (l>>4)*8 + i)][n = nt*16 + (l&15)].
// Block 0 also zeroes bins + the finalize counter.
// ---------------------------------------------------------------------------
__global__ void pinn_pack(const float* __restrict__ W1, const float* __restrict__ W2,
                          const float* __restrict__ W3, unsigned short* __restrict__ Bp,
                          float* __restrict__ bins)
{
    if (blockIdx.x == 0) {
        bins[threadIdx.x] = 0.f;
        bins[threadIdx.x + 256] = 0.f;
        if (threadIdx.x == 0) *(unsigned*)(bins + 512) = 0u;
    }
    const int id = blockIdx.x * 256 + threadIdx.x;   // 0..24575
    const int lane = id & 63;
    const int nt   = (id >> 6) & 15;
    const int kc   = (id >> 10) & 7;
    const int l    = id >> 13;                        // 0..2
    const float* W = (l == 0) ? W1 : ((l == 1) ? W2 : W3);
    const int n  = nt * 16 + (lane & 15);
    unsigned short hi[8], lo[8];
    #pragma unroll
    for (int i = 0; i < 8; ++i) {
        const int kslot = kc * 32 + (lane >> 4) * 8 + i;
        const int korig = ((kslot >> 6) & 3) * 64 + (kslot & 3) * 16 + ((kslot >> 2) & 15);
        const float x = W[(size_t)korig * HIDDEN + n];
        const unsigned short h = bf16_rne(x);
        hi[i] = h;
        lo[i] = bf16_rne(x - bf16f(h));
    }
    const size_t bh = ((((size_t)(l * 2 + 0) * 8 + kc) * 16 + nt) * 64 + lane) * 8;
    const size_t bl = ((((size_t)(l * 2 + 1) * 8 + kc) * 16 + nt) * 64 + lane) * 8;
    *(s8v*)&Bp[bh] = *(const s8v*)hi;
    *(s8v*)&Bp[bl] = *(const s8v*)lo;
}

// ---------------------------------------------------------------------------
// Main: second-order forward-mode MLP via split-bf16 MFMA + physics.
// Nonlinearity runs IN C-REGISTERS (row remap makes all 7 streams of a point
// lane-local); boundary writes A-frags directly (28 conflict-free b64).
// ---------------------------------------------------------------------------
__global__ __launch_bounds__(THREADS, 2)
void pinn_main(const float* __restrict__ W0, const float* __restrict__ b0,
               const float* __restrict__ b1, const float* __restrict__ b2,
               const float* __restrict__ b3,
               const float* __restrict__ W4, const float* __restrict__ b4,
               const float* __restrict__ xin, const float* __restrict__ tin,
               const unsigned short* __restrict__ Bp,
               float* __restrict__ bins, float* __restrict__ out)
{
    __shared__ __align__(16) unsigned char LB[65472];   // 2 parts x 62 rows x 264 shorts
    short* __restrict__ AhS = (short*)LB;
    short* __restrict__ AlS = (short*)(LB + AROWS * LDA * 2);
    float* __restrict__ Zf  = (float*)LB;               // final-H alias (56x264 f32)

    const int tid  = threadIdx.x;
    const int lane = tid & 63;
    const int w    = tid >> 6;          // wave 0..3
    const int c    = lane & 15;
    const int g    = lane >> 4;
    const int pt0  = blockIdx.x * PPB;
    unsigned* cnt  = (unsigned*)(bins + 512);

    // ---- layer 0 (3 -> 256): thread (c0,w0i) covers slots 4*(c0+16*w0i)+nn,
    //      i.e. cols j = 64*w0i + c0 + 16*nn; points {pp, pp+4} ----
    {
        const int c0i = tid & 15, w0i = (tid >> 4) & 3, pp = tid >> 6;
        float w0v[4], w1v[4], w2v[4], bbv[4];
        #pragma unroll
        for (int nn = 0; nn < 4; ++nn) {
            const int j = w0i * 64 + 16 * nn + c0i;
            w0v[nn] = W0[j]; w1v[nn] = W0[HIDDEN + j]; w2v[nn] = W0[2 * HIDDEN + j];
            bbv[nn] = b0[j];
        }
        const int sbase = 4 * (c0i + 16 * w0i);
        #pragma unroll
        for (int e = 0; e < 2; ++e) {
            const int p = pp + 4 * e;
            const float x0 = xin[(pt0 + p) * 2 + 0];
            const float x1 = xin[(pt0 + p) * 2 + 1];
            const float tt = tin[pt0 + p];
            s4v hi[7], lo[7];
            #pragma unroll
            for (int nn = 0; nn < 4; ++nn) {
                const float z  = fmaf(x0, w0v[nn], fmaf(x1, w1v[nn], fmaf(tt, w2v[nn], bbv[nn])));
                const float a  = tanhf(z);
                const float st = 1.f - a * a;
                const float m2 = -2.f * a * st;
                float v[7];
                v[0] = a;
                v[1] = st * w0v[nn]; v[2] = st * w1v[nn]; v[3] = st * w2v[nn];
                v[4] = m2 * w0v[nn] * w0v[nn];
                v[5] = m2 * w0v[nn] * w1v[nn];
                v[6] = m2 * w1v[nn] * w1v[nn];
                #pragma unroll
                for (int s = 0; s < 7; ++s) {
                    const unsigned short h = bf16_rne(v[s]);
                    hi[s][nn] = (short)h;
                    lo[s][nn] = (short)bf16_rne(v[s] - bf16f(h));
                }
            }
            #pragma unroll
            for (int s = 0; s < 7; ++s) {
                const int r = rowof(s, p);
                *(s4v*)&AhS[r * LDA + sbase] = hi[s];
                *(s4v*)&AlS[r * LDA + sbase] = lo[s];
            }
        }
        if (pp == 0) {                       // zero garbage rows 50,51,54,55,58,59
            const s4v z4 = {0, 0, 0, 0};
            #pragma unroll
            for (int b = 0; b < 3; ++b)
                #pragma unroll
                for (int d = 2; d < 4; ++d) {
                    const int r = 48 + 4 * b + d;
                    *(s4v*)&AhS[r * LDA + sbase] = z4;
                    *(s4v*)&AlS[r * LDA + sbase] = z4;
                }
        }
    }
    __syncthreads();

    // per-thread A-frag row offsets (mt=3 clamps c>=14 -> row 48)
    int aoff[4];
    #pragma unroll
    for (int mt = 0; mt < 3; ++mt) aoff[mt] = (16 * mt + c) * LDA + g * 8;
    aoff[3] = (48 + ((c >= 14) ? 0 : c)) * LDA + g * 8;

    // ---- hidden layers: split-bf16 MFMA matmul + in-register nonlinearity ----
    for (int l = 0; l < 3; ++l) {
        f32x4 acc[4][4];
        #pragma unroll
        for (int mt = 0; mt < 4; ++mt)
            #pragma unroll
            for (int nn = 0; nn < 4; ++nn) acc[mt][nn] = (f32x4)0.f;

        const size_t lbase = (size_t)l * 2 * 8 * 16 * 64 * 8;
        #pragma unroll
        for (int kc = 0; kc < 8; ++kc) {
            s8v ah[4], al[4];
            #pragma unroll
            for (int mt = 0; mt < 4; ++mt) {
                ah[mt] = *(const s8v*)&AhS[aoff[mt] + kc * 32];
                al[mt] = *(const s8v*)&AlS[aoff[mt] + kc * 32];
            }
            s8v bh[4], bl[4];
            #pragma unroll
            for (int nn = 0; nn < 4; ++nn) {
                const int nt = w * 4 + nn;
                const size_t oh = lbase + (((size_t)kc * 16 + nt) * 64 + lane) * 8;
                const size_t ol = oh + (size_t)8 * 16 * 64 * 8;
                bh[nn] = *(const s8v*)&Bp[oh];
                bl[nn] = *(const s8v*)&Bp[ol];
            }
            #pragma unroll
            for (int mt = 0; mt < 4; ++mt)
                #pragma unroll
                for (int nn = 0; nn < 4; ++nn) {
                    acc[mt][nn] = __builtin_amdgcn_mfma_f32_16x16x32_bf16(ah[mt], bh[nn], acc[mt][nn], 0, 0, 0);
                    acc[mt][nn] = __builtin_amdgcn_mfma_f32_16x16x32_bf16(ah[mt], bl[nn], acc[mt][nn], 0, 0, 0);
                    acc[mt][nn] = __builtin_amdgcn_mfma_f32_16x16x32_bf16(al[mt], bh[nn], acc[mt][nn], 0, 0, 0);
                }
        }
        __syncthreads();                     // all A reads done -> safe to overwrite

        // ---- boundary: lane (g,c) owns points {2g,2g+1}, cols 64w+16nn+c ----
        const float* bias = (l == 0) ? b1 : (l == 1) ? b2 : b3;
        float bbv[4];
        #pragma unroll
        for (int nn = 0; nn < 4; ++nn) bbv[nn] = bias[64 * w + 16 * nn + c];
        const int sbase = 4 * (c + 16 * w);

        #pragma unroll
        for (int e = 0; e < 2; ++e) {
            const int p = 2 * g + e;
            float v[7][4];
            #pragma unroll
            for (int nn = 0; nn < 4; ++nn) {
                const float z0 = acc[0][nn][2 * e + 0] + bbv[nn];
                const float z1 = acc[0][nn][2 * e + 1];
                const float z2 = acc[1][nn][2 * e + 0];
                const float z3 = acc[1][nn][2 * e + 1];
                const float z4 = acc[2][nn][2 * e + 0];
                const float z5 = acc[2][nn][2 * e + 1];
                const float z6 = acc[3][nn][e];
                const float a  = tanhf(z0);
                const float st = 1.f - a * a;
                const float m2 = -2.f * a * st;
                v[0][nn] = a;
                v[1][nn] = st * z1; v[2][nn] = st * z2; v[3][nn] = st * z3;
                v[4][nn] = fmaf(m2 * z1, z1, st * z4);
                v[5][nn] = fmaf(m2 * z1, z2, st * z5);
                v[6][nn] = fmaf(m2 * z2, z2, st * z6);
            }
            if (l < 2) {
                #pragma unroll
                for (int s = 0; s < 7; ++s) {
                    s4v hi, lo;
                    #pragma unroll
                    for (int nn = 0; nn < 4; ++nn) {
                        const unsigned short h = bf16_rne(v[s][nn]);
                        hi[nn] = (short)h;
                        lo[nn] = (short)bf16_rne(v[s][nn] - bf16f(h));
                    }
                    const int r = rowof(s, p);
                    *(s4v*)&AhS[r * LDA + sbase] = hi;
                    *(s4v*)&AlS[r * LDA + sbase] = lo;
                }
            } else {
                #pragma unroll
                for (int s = 0; s < 7; ++s) {
                    f32x4 vv = {v[s][0], v[s][1], v[s][2], v[s][3]};
                    *(f32x4*)&Zf[(8 * s + p) * LDZ + sbase] = vv;   // final H, f32
                }
            }
        }
        __syncthreads();
    }

    // ---- final layer (256 -> 3): half-wave per point, slot-k + W4 gather ----
    const int h  = (lane >> 5);
    const int la = lane & 31;
    const int p  = w * 2 + h;

    float part[7][3];
    #pragma unroll
    for (int s = 0; s < 7; ++s)
        #pragma unroll
        for (int m = 0; m < 3; ++m) part[s][m] = 0.f;

    #pragma unroll
    for (int i = 0; i < 8; ++i) {
        const int kslot = la + 32 * i;
        const int korig = ((kslot >> 6) & 3) * 64 + (kslot & 3) * 16 + ((kslot >> 2) & 15);
        const float w40 = W4[korig * 3 + 0], w41 = W4[korig * 3 + 1], w42 = W4[korig * 3 + 2];
        #pragma unroll
        for (int s = 0; s < 7; ++s) {
            const float hk = Zf[(8 * s + p) * LDZ + kslot];
            part[s][0] = fmaf(hk, w40, part[s][0]);
            part[s][1] = fmaf(hk, w41, part[s][1]);
            part[s][2] = fmaf(hk, w42, part[s][2]);
        }
    }
    #pragma unroll
    for (int s = 0; s < 7; ++s)
        #pragma unroll
        for (int m = 0; m < 3; ++m) {
            float v = part[s][m];
            #pragma unroll
            for (int off = 16; off > 0; off >>= 1) v += __shfl_xor(v, off);
            part[s][m] = v;
        }

    // ---- physics (identical math to r5/r6, verified) ----
    const float x0 = xin[(pt0 + p) * 2 + 0];
    const float x1 = xin[(pt0 + p) * 2 + 1];
    const float tt = tin[pt0 + p];

    const float V0 = part[0][0] + b4[0];
    const float V1 = part[0][1] + b4[1];
    const float V2 = part[0][2] + b4[2];
    const float J00 = part[1][0], J01 = part[2][0], J0t = part[3][0];
    const float J10 = part[1][1], J11 = part[2][1];
    const float J20 = part[1][2], J21 = part[2][2];
    const float H000 = part[4][0], H011 = part[6][0];
    const float H100 = part[4][1], H101 = part[5][1], H111 = part[6][1];
    const float H200 = part[4][2], H201 = part[5][2], H211 = part[6][2];

    const float phi = 1.f / (1.f + expf(-V0));
    const float om  = 1.f - phi;
    const float sp  = phi * om;
    const float spp = sp * (1.f - 2.f * phi);
    const float phx0 = sp * J00, phx1 = sp * J01, dphidt = sp * J0t;
    const float lap = spp * (J00 * J00 + J01 * J01) + sp * (H000 + H011);

    const float ld = tt;
    const float qq = x1 * (x1 - 1.f), qp = 2.f * x1 - 1.f;

    const float ux0 = qq * J10 * ld * (1.f / 3.f);
    const float ux1 = (qp * V1 + qq * J11) * ld * (1.f / 3.f);
    const float uy0 = qq * J20 * ld;
    const float uy1 = (qp * V2 + qq * J21) * ld + ld;

    const float e00 = ux0, e11 = uy1, e01 = 0.5f * (ux1 + uy0);
    const float tr = e00 + e11;

    const float ux_00 = qq * H100 * ld * (1.f / 3.f);
    const float ux_01 = (qp * J10 + qq * H101) * ld * (1.f / 3.f);
    const float ux_11 = (2.f * V1 + 2.f * qp * J11 + qq * H111) * ld * (1.f / 3.f);
    const float uy_00 = qq * H200 * ld;
    const float uy_01 = (qp * J20 + qq * H201) * ld;
    const float uy_11 = (2.f * V2 + 2.f * qp * J21 + qq * H211) * ld;

    const float de00_0 = ux_00, de00_1 = ux_01;
    const float de11_0 = uy_01, de11_1 = uy_11;
    const float de01_0 = 0.5f * (ux_01 + uy_00), de01_1 = 0.5f * (ux_11 + uy_01);
    const float dtr_0 = de00_0 + de11_0, dtr_1 = de00_1 + de11_1;

    const float kk = 2.f;
    const float rtr = fmaxf(tr, 0.f), rntr = fmaxf(-tr, 0.f);
    const float Hp = (tr > 0.f) ? 1.f : 0.f, Hn = (tr < 0.f) ? 1.f : 0.f;

    const float dv = 0.5f * (e00 - e11);
    const float sp00 = kk * rtr + 2.f * dv;
    const float sp11 = kk * rtr - 2.f * dv;
    const float sp01 = 2.f * e01;
    const float snd  = -kk * rntr;

    const float dsp00_0 = kk * Hp * dtr_0 + 2.f * (de00_0 - 0.5f * dtr_0);
    const float dsp01_0 = 2.f * de01_0;
    const float dsp01_1 = 2.f * de01_1;
    const float dsp11_1 = kk * Hp * dtr_1 + 2.f * (de11_1 - 0.5f * dtr_1);
    const float dsn_0 = kk * Hn * dtr_0, dsn_1 = kk * Hn * dtr_1;

    const float cc  = om * om, gg = cc + 1e-6f;
    const float dc0 = -2.f * om * phx0, dc1 = -2.f * om * phx1;
    const float gpc = gg + cc, cg = cc * gg;

    const float res0 = dc0 * gpc * sp00 + cg * dsp00_0 + dc0 * snd + cc * dsn_0
                     + dc1 * gpc * sp01 + cg * dsp01_1;
    const float res1 = dc0 * gpc * sp01 + cg * dsp01_0
                     + dc1 * gpc * sp11 + cg * dsp11_1 + dc1 * snd + cc * dsn_1;

    const float psip = rtr * rtr + 0.5f * (e00 - e11) * (e00 - e11) + 2.f * e01 * e01;
    const float psin = rntr * rntr;

    const float GCc = 0.0027f, LL = 0.02f;
    const float pf = GCc * (phi / LL - LL * lap) - 2.f * om * psip;
    const bool maskp = (fabsf(dphidt) <= 1e-3f) && (fabsf(phi - 1.f) > 1e-3f);
    const bool maskn = fabsf(phi - 1.f) <= 1e-3f;
    const float respf = maskp ? fmaxf(-pf, 0.f) : (maskn ? fmaxf(pf, 0.f) : pf);

    const float rese = om * 2.f * psip + psin
                     + GCc * (phi * phi / (2.f * LL)
                              + 0.5f * LL * (phx0 * phx0 + phx1 * phx1));
    const float irr = fmaxf(-dphidt, 0.f);

    if (la == 0) {
        float* bin = bins + (blockIdx.x & (NBINS - 1)) * 8;
        atomicAdd(bin + 0, res0 * res0);
        atomicAdd(bin + 1, res1 * res1);
        atomicAdd(bin + 2, respf * respf);
        atomicAdd(bin + 3, rese);
        atomicAdd(bin + 4, irr);
    }

    // ---- fused finalize: last block reduces the bins ----
    __syncthreads();                          // all atomics of this block issued & drained
    volatile unsigned* flg = (volatile unsigned*)(LB + 65024);
    if (tid == 0) {
        const unsigned old = atomicAdd(cnt, 1u);
        *flg = old;
    }
    __syncthreads();
    if (*flg == NBLK - 1) {
        if (tid < 64) {
            float s0 = atomicAdd(&bins[tid * 8 + 0], 0.f);
            float s1 = atomicAdd(&bins[tid * 8 + 1], 0.f);
            float s2 = atomicAdd(&bins[tid * 8 + 2], 0.f);
            float s3 = atomicAdd(&bins[tid * 8 + 3], 0.f);
            float s4 = atomicAdd(&bins[tid * 8 + 4], 0.f);
            #pragma unroll
            for (int off = 32; off > 0; off >>= 1) {
                s0 += __shfl_xor(s0, off);
                s1 += __shfl_xor(s1, off);
                s2 += __shfl_xor(s2, off);
                s3 += __shfl_xor(s3, off);
                s4 += __shfl_xor(s4, off);
            }
            if (tid == 0) {
                const float inv_n = 1.f / (float)N_PTS;
                const float mse0 = s0 * inv_n, mse1 = s1 * inv_n;
                const float wm = 0.5f * (mse0 + mse1);
                out[0] = wm * mse0 / (mse0 + 1e-6f) + wm * mse1 / (mse1 + 1e-6f);
                out[1] = s2 * inv_n;
                out[2] = logf(s3);
                out[3] = s4 * inv_n;
            }
        }
    }
}

// ---------------------------------------------------------------------------
extern "C" void kernel_launch(void* const* d_in, const int* in_sizes, int n_in,
                              void* d_out, int out_size, void* d_ws, size_t ws_size,
                              hipStream_t stream)
{
    const float *W[5], *b[5];
    if (in_sizes[1] == HIDDEN) {
        for (int i = 0; i < 5; ++i) {           // dict order W0,b0,W1,b1,...
            W[i] = (const float*)d_in[2 * i];
            b[i] = (const float*)d_in[2 * i + 1];
        }
    } else {
        for (int i = 0; i < 5; ++i) {           // signature order W0..W4, b0..b4
            W[i] = (const float*)d_in[i];
            b[i] = (const float*)d_in[5 + i];
        }
    }
    const float* x = (const float*)d_in[10];
    const float* t = (const float*)d_in[11];
    float* bins = (float*)d_ws;
    unsigned short* Bp = (unsigned short*)((char*)d_ws + BP_OFF);

    pinn_pack<<<96, 256, 0, stream>>>(W[1], W[2], W[3], Bp, bins);
    pinn_main<<<NBLK, THREADS, 0, stream>>>(W[0], b[0], b[1], b[2], b[3],
                                            W[4], b[4], x, t, Bp, bins,
                                            (float*)d_out);
}